// Round 1
// baseline (1731.642 us; speedup 1.0000x reference)
//
#include <hip/hip_runtime.h>
#include <math.h>

#define D_MODEL 1536
#define NH      8
#define HD      192
#define BB      16
#define LL      64
#define UU      64
#define NTOK    1024
#define EPSF    1e-5f

typedef __bf16 bf16;
typedef __bf16 bf16x4_t __attribute__((ext_vector_type(4)));
typedef __bf16 bf16x8_t __attribute__((ext_vector_type(8)));
typedef float  f32x4_t  __attribute__((ext_vector_type(4)));

// ---------------- pooling + pos embed ----------------
__global__ __launch_bounds__(256)
void pool_kernel(const float* __restrict__ x, const float* __restrict__ pw,
                 const float* __restrict__ pb, const float* __restrict__ pos,
                 float* __restrict__ mem, float* __restrict__ h0)
{
    __shared__ float slog[UU];
    __shared__ float satt[UU];
    const int t = threadIdx.x, wave = t >> 6, lane = t & 63;
    const int bl = blockIdx.x;          // b*64 + l
    const int l = bl & (LL - 1);
    const float* xb = x + (size_t)bl * UU * D_MODEL;

    float pwr[24];
#pragma unroll
    for (int j = 0; j < 24; ++j) pwr[j] = pw[lane + j * 64];

    for (int ui = 0; ui < 16; ++ui) {
        const int u = wave * 16 + ui;
        const float* xu = xb + (size_t)u * D_MODEL;
        float a = 0.f;
#pragma unroll
        for (int j = 0; j < 24; ++j) a += xu[lane + j * 64] * pwr[j];
#pragma unroll
        for (int off = 32; off; off >>= 1) a += __shfl_xor(a, off, 64);
        if (lane == 0) slog[u] = a + pb[0];
    }
    __syncthreads();
    float m = -__builtin_inff();
    for (int u = 0; u < UU; ++u) m = fmaxf(m, slog[u]);
    float s = 0.f;
    for (int u = 0; u < UU; ++u) s += __expf(slog[u] - m);
    if (t < UU) satt[t] = __expf(slog[t] - m) / s;
    __syncthreads();
#pragma unroll
    for (int j = 0; j < 6; ++j) {
        const int d = t + j * 256;
        float acc = 0.f;
        for (int u = 0; u < UU; ++u) acc += satt[u] * xb[(size_t)u * D_MODEL + d];
        const float v = acc + pos[l * D_MODEL + d];
        mem[(size_t)bl * D_MODEL + d] = v;
        h0 [(size_t)bl * D_MODEL + d] = v;
    }
}

// ---------------- bf16 MFMA GEMM: C = A(M,K) @ W(N,K)^T + bias, opt relu ----
#define BM 128
#define BN 128
#define BKK 32
#define LDT 72   // LDS row stride in bf16 elems (144 B, 16B aligned, conflict-free frags)

__global__ __launch_bounds__(256, 2)
void gemm_kernel(const float* __restrict__ A, const float* __restrict__ W,
                 const float* __restrict__ bias, float* __restrict__ C,
                 int M, int N, int K, int relu)
{
    __shared__ bf16 As[BM * LDT];
    __shared__ bf16 Bs[BN * LDT];
    const int t = threadIdx.x;
    const int wave = t >> 6, lane = t & 63;
    const int n0 = blockIdx.x * BN, m0 = blockIdx.y * BM;
    const int wr = wave >> 1, wc = wave & 1;     // 2x2 waves, 64x64 each
    const int frow = lane & 15, kb = lane >> 4;

    f32x4_t acc[4][4] = {};

    for (int k0 = 0; k0 < K; k0 += BKK) {
#pragma unroll
        for (int i = 0; i < 4; ++i) {
            const int idx = t + i * 256;        // 0..1023
            const int r = idx >> 3, c4 = idx & 7;
            const float4 av = *(const float4*)(A + (size_t)(m0 + r) * K + k0 + c4 * 4);
            bf16x4_t a4 = { (bf16)av.x, (bf16)av.y, (bf16)av.z, (bf16)av.w };
            *(bf16x4_t*)(&As[r * LDT + c4 * 4]) = a4;
            const float4 wv = *(const float4*)(W + (size_t)(n0 + r) * K + k0 + c4 * 4);
            bf16x4_t b4 = { (bf16)wv.x, (bf16)wv.y, (bf16)wv.z, (bf16)wv.w };
            *(bf16x4_t*)(&Bs[r * LDT + c4 * 4]) = b4;
        }
        __syncthreads();
        bf16x8_t af[4], bfr[4];
#pragma unroll
        for (int mi = 0; mi < 4; ++mi)
            af[mi] = *(const bf16x8_t*)(&As[(wr * 64 + mi * 16 + frow) * LDT + kb * 8]);
#pragma unroll
        for (int ni = 0; ni < 4; ++ni)
            bfr[ni] = *(const bf16x8_t*)(&Bs[(wc * 64 + ni * 16 + frow) * LDT + kb * 8]);
#pragma unroll
        for (int mi = 0; mi < 4; ++mi)
#pragma unroll
            for (int ni = 0; ni < 4; ++ni)
                acc[mi][ni] = __builtin_amdgcn_mfma_f32_16x16x32_bf16(af[mi], bfr[ni], acc[mi][ni], 0, 0, 0);
        __syncthreads();
    }

    const int crow = m0 + wr * 64 + (lane >> 4) * 4;
    const int ccol = n0 + wc * 64 + (lane & 15);
#pragma unroll
    for (int mi = 0; mi < 4; ++mi)
#pragma unroll
        for (int ni = 0; ni < 4; ++ni) {
            const int col = ccol + ni * 16;
            const float bv = bias[col];
            const int rb = crow + mi * 16;
#pragma unroll
            for (int j = 0; j < 4; ++j) {
                float v = acc[mi][ni][j] + bv;
                if (relu) v = fmaxf(v, 0.f);
                C[(size_t)(rb + j) * N + col] = v;
            }
        }
}

// ---------------- attention core (per b,h block) ----------------
template<bool CAUSAL>
__global__ __launch_bounds__(256)
void attn_kernel(const float* __restrict__ qbuf, int qstride, int qoff0,
                 const float* __restrict__ kbuf, int kstride, int koff0,
                 const float* __restrict__ vbuf, int vstride, int voff0,
                 float* __restrict__ out)
{
    __shared__ float kv[HD * 64];    // K phase: K^T swizzled [d][k]; V phase: [k][d] linear
    __shared__ float sc[64 * 64];    // P (post-softmax)
    const int t = threadIdx.x, wave = t >> 6, lane = t & 63;
    const int b = blockIdx.x >> 3, hh = blockIdx.x & 7;
    const int t0 = b * 64;
    const float scale = rsqrtf((float)HD);

    // stage K transposed + XOR swizzle: K[r][c] -> kv[c*64 + (r ^ (c&31))]
    for (int i = 0; i < 48; ++i) {
        const int idx = t + i * 256;
        const int r = idx / HD, c = idx % HD;
        kv[c * 64 + (r ^ (c & 31))] = kbuf[(size_t)(t0 + r) * kstride + koff0 + hh * HD + c];
    }
    __syncthreads();

    // scores: wave handles q rows [wave*16, +16); lane = k index
    for (int qi = 0; qi < 16; ++qi) {
        const int q = wave * 16 + qi;
        const float* qr = qbuf + (size_t)(t0 + q) * qstride + qoff0 + hh * HD;
        float a = 0.f;
#pragma unroll 8
        for (int d = 0; d < HD; ++d)
            a += qr[d] * kv[d * 64 + (lane ^ (d & 31))];
        a *= scale;
        if (CAUSAL && lane > q) a = -__builtin_inff();
        float m = a;
#pragma unroll
        for (int off = 32; off; off >>= 1) m = fmaxf(m, __shfl_xor(m, off, 64));
        float e = (CAUSAL && lane > q) ? 0.f : __expf(a - m);
        float s = e;
#pragma unroll
        for (int off = 32; off; off >>= 1) s += __shfl_xor(s, off, 64);
        sc[q * 64 + lane] = e / s;
    }
    __syncthreads();

    // stage V linear [k][d]
    for (int i = 0; i < 48; ++i) {
        const int idx = t + i * 256;
        const int r = idx / HD, c = idx % HD;
        kv[r * HD + c] = vbuf[(size_t)(t0 + r) * vstride + voff0 + hh * HD + c];
    }
    __syncthreads();

    // PV: wave handles q rows [wave*16,+16); lane covers d = lane + 64*dj
    for (int qi = 0; qi < 16; ++qi) {
        const int q = wave * 16 + qi;
        float o0 = 0.f, o1 = 0.f, o2 = 0.f;
#pragma unroll 8
        for (int k = 0; k < 64; ++k) {
            const float p = sc[q * 64 + k];
            o0 += p * kv[k * HD + lane];
            o1 += p * kv[k * HD + 64 + lane];
            o2 += p * kv[k * HD + 128 + lane];
        }
        float* op = out + (size_t)(t0 + q) * D_MODEL + hh * HD;
        op[lane] = o0; op[64 + lane] = o1; op[128 + lane] = o2;
    }
}

// ---------------- residual + LayerNorm ----------------
__global__ __launch_bounds__(256)
void ln_kernel(const float* __restrict__ a, const float* __restrict__ r,
               const float* __restrict__ w, const float* __restrict__ bb,
               float* __restrict__ out)
{
    __shared__ float red[8];
    const int tok = blockIdx.x, t = threadIdx.x;
    const int wave = t >> 6, lane = t & 63;
    const float* ap = a + (size_t)tok * D_MODEL;
    const float* rp = r + (size_t)tok * D_MODEL;
    float v[6];
    float s = 0.f;
#pragma unroll
    for (int j = 0; j < 6; ++j) { v[j] = ap[t + j * 256] + rp[t + j * 256]; s += v[j]; }
#pragma unroll
    for (int off = 32; off; off >>= 1) s += __shfl_xor(s, off, 64);
    if (lane == 0) red[wave] = s;
    __syncthreads();
    const float mu = (red[0] + red[1] + red[2] + red[3]) * (1.f / D_MODEL);
    float s2 = 0.f;
#pragma unroll
    for (int j = 0; j < 6; ++j) { const float d = v[j] - mu; s2 += d * d; }
#pragma unroll
    for (int off = 32; off; off >>= 1) s2 += __shfl_xor(s2, off, 64);
    if (lane == 0) red[4 + wave] = s2;
    __syncthreads();
    const float var = (red[4] + red[5] + red[6] + red[7]) * (1.f / D_MODEL);
    const float inv = rsqrtf(var + EPSF);
#pragma unroll
    for (int j = 0; j < 6; ++j) {
        const int d = t + j * 256;
        out[(size_t)tok * D_MODEL + d] = (v[j] - mu) * inv * w[d] + bb[d];
    }
}

// ---------------- output slice h[:, :63, :] ----------------
__global__ __launch_bounds__(256)
void slice_kernel(const float* __restrict__ h, float* __restrict__ out)
{
    const int i = blockIdx.x * 256 + threadIdx.x;   // float4 index
    if (i >= BB * 63 * (D_MODEL / 4)) return;
    const int d4 = i % (D_MODEL / 4);
    const int tl = i / (D_MODEL / 4);
    const int b = tl / 63, l = tl % 63;
    ((float4*)out)[i] = ((const float4*)(h + (size_t)(b * 64 + l) * D_MODEL))[d4];
}

extern "C" void kernel_launch(void* const* d_in, const int* in_sizes, int n_in,
                              void* d_out, int out_size, void* d_ws, size_t ws_size,
                              hipStream_t stream)
{
    (void)in_sizes; (void)n_in; (void)out_size; (void)ws_size;
    const float* x        = (const float*)d_in[0];
    const float* pooler_w = (const float*)d_in[1];
    const float* pooler_b = (const float*)d_in[2];
    const float* pos      = (const float*)d_in[3];
    const float* sa_qkv_w = (const float*)d_in[4];
    const float* sa_qkv_b = (const float*)d_in[5];
    const float* sa_out_w = (const float*)d_in[6];
    const float* sa_out_b = (const float*)d_in[7];
    const float* ca_qkv_w = (const float*)d_in[8];
    const float* ca_qkv_b = (const float*)d_in[9];
    const float* ca_out_w = (const float*)d_in[10];
    const float* ca_out_b = (const float*)d_in[11];
    const float* ff1_w    = (const float*)d_in[12];
    const float* ff1_b    = (const float*)d_in[13];
    const float* ff2_w    = (const float*)d_in[14];
    const float* ff2_b    = (const float*)d_in[15];
    const float* ln1_w    = (const float*)d_in[16];
    const float* ln1_b    = (const float*)d_in[17];
    const float* ln2_w    = (const float*)d_in[18];
    const float* ln2_b    = (const float*)d_in[19];
    const float* ln3_w    = (const float*)d_in[20];
    const float* ln3_b    = (const float*)d_in[21];
    float* outp = (float*)d_out;

    float* wsf   = (float*)d_ws;
    float* mem   = wsf;                 // 1024*1536
    float* h     = mem   + (size_t)NTOK * D_MODEL;
    float* qkv   = h     + (size_t)NTOK * D_MODEL;   // 1024*4608
    float* attno = qkv   + (size_t)NTOK * 4608;
    float* proj  = attno + (size_t)NTOK * D_MODEL;
    float* ffmid = proj  + (size_t)NTOK * D_MODEL;   // 1024*2048
    float* ckv   = ffmid + (size_t)NTOK * 2048;      // 1024*3072
    float* cq    = ckv   + (size_t)NTOK * 3072;      // 1024*1536

    pool_kernel<<<NTOK, 256, 0, stream>>>(x, pooler_w, pooler_b, pos, mem, h);

    for (int i = 0; i < 2; ++i) {
        // self-attention
        gemm_kernel<<<dim3(36, 8), 256, 0, stream>>>(
            h, sa_qkv_w + (size_t)i * 4608 * D_MODEL, sa_qkv_b + (size_t)i * 4608,
            qkv, NTOK, 4608, D_MODEL, 0);
        attn_kernel<true><<<BB * NH, 256, 0, stream>>>(
            qkv, 4608, 0, qkv, 4608, 1536, qkv, 4608, 3072, attno);
        gemm_kernel<<<dim3(12, 8), 256, 0, stream>>>(
            attno, sa_out_w + (size_t)i * D_MODEL * D_MODEL, sa_out_b + (size_t)i * D_MODEL,
            proj, NTOK, D_MODEL, D_MODEL, 0);
        ln_kernel<<<NTOK, 256, 0, stream>>>(h, proj, ln1_w + i * D_MODEL, ln1_b + i * D_MODEL, h);

        // cross-attention
        gemm_kernel<<<dim3(12, 8), 256, 0, stream>>>(
            h, ca_qkv_w + (size_t)i * 4608 * D_MODEL, ca_qkv_b + (size_t)i * 4608,
            cq, NTOK, D_MODEL, D_MODEL, 0);
        gemm_kernel<<<dim3(24, 8), 256, 0, stream>>>(
            mem, ca_qkv_w + (size_t)i * 4608 * D_MODEL + (size_t)1536 * D_MODEL,
            ca_qkv_b + (size_t)i * 4608 + 1536,
            ckv, NTOK, 3072, D_MODEL, 0);
        attn_kernel<false><<<BB * NH, 256, 0, stream>>>(
            cq, 1536, 0, ckv, 3072, 0, ckv, 3072, 1536, attno);
        gemm_kernel<<<dim3(12, 8), 256, 0, stream>>>(
            attno, ca_out_w + (size_t)i * D_MODEL * D_MODEL, ca_out_b + (size_t)i * D_MODEL,
            proj, NTOK, D_MODEL, D_MODEL, 0);
        ln_kernel<<<NTOK, 256, 0, stream>>>(h, proj, ln2_w + i * D_MODEL, ln2_b + i * D_MODEL, h);

        // feed-forward
        gemm_kernel<<<dim3(16, 8), 256, 0, stream>>>(
            h, ff1_w + (size_t)i * 2048 * D_MODEL, ff1_b + (size_t)i * 2048,
            ffmid, NTOK, 2048, D_MODEL, 1);
        gemm_kernel<<<dim3(12, 8), 256, 0, stream>>>(
            ffmid, ff2_w + (size_t)i * D_MODEL * 2048, ff2_b + (size_t)i * D_MODEL,
            proj, NTOK, D_MODEL, 2048, 0);
        ln_kernel<<<NTOK, 256, 0, stream>>>(h, proj, ln3_w + i * D_MODEL, ln3_b + i * D_MODEL, h);
    }

    slice_kernel<<<(BB * 63 * (D_MODEL / 4) + 255) / 256, 256, 0, stream>>>(h, outp);
}

// Round 2
// 1079.674 us; speedup vs baseline: 1.6039x; 1.6039x over previous
//
#include <hip/hip_runtime.h>
#include <math.h>

#define D_MODEL 1536
#define NH      8
#define HD      192
#define BB      16
#define LL      64
#define UU      64
#define NTOK    1024
#define EPSF    1e-5f

typedef __bf16 bf16;
typedef __bf16 bf16x4_t __attribute__((ext_vector_type(4)));
typedef __bf16 bf16x8_t __attribute__((ext_vector_type(8)));
typedef float  f32x4_t  __attribute__((ext_vector_type(4)));

__device__ __forceinline__ void gload_lds16(const bf16* g, bf16* l) {
    __builtin_amdgcn_global_load_lds((const __attribute__((address_space(1))) void*)g,
                                     (__attribute__((address_space(3))) void*)l, 16, 0, 0);
}

// ---------------- weight fp32 -> bf16 convert ----------------
__global__ __launch_bounds__(256)
void cvt_kernel(const float* __restrict__ s, bf16* __restrict__ d, int n4)
{
    int i = blockIdx.x * 256 + threadIdx.x;
    const int stride = gridDim.x * 256;
    for (; i < n4; i += stride) {
        const float4 v = ((const float4*)s)[i];
        bf16x4_t o = { (bf16)v.x, (bf16)v.y, (bf16)v.z, (bf16)v.w };
        ((bf16x4_t*)d)[i] = o;
    }
}

// ---------------- pooling: logits ----------------
__global__ __launch_bounds__(256)
void logits_kernel(const float* __restrict__ x, const float* __restrict__ pw,
                   const float* __restrict__ pb, float* __restrict__ logits)
{
    const int t = threadIdx.x, wave = t >> 6, lane = t & 63;
    const float4* pw4 = (const float4*)pw;
    float4 pwr[6];
#pragma unroll
    for (int j = 0; j < 6; ++j) pwr[j] = pw4[lane + j * 64];
    const int row0 = blockIdx.x * 16 + wave * 4;
#pragma unroll
    for (int q = 0; q < 4; ++q) {
        const int row = row0 + q;
        const float4* xr = (const float4*)(x + (size_t)row * D_MODEL);
        float a = 0.f;
#pragma unroll
        for (int j = 0; j < 6; ++j) {
            const float4 v = xr[lane + j * 64];
            a += v.x * pwr[j].x + v.y * pwr[j].y + v.z * pwr[j].z + v.w * pwr[j].w;
        }
#pragma unroll
        for (int off = 32; off; off >>= 1) a += __shfl_xor(a, off, 64);
        if (lane == 0) logits[row] = a + pb[0];
    }
}

// ---------------- pooling: softmax over u ----------------
__global__ __launch_bounds__(256)
void usoftmax_kernel(const float* __restrict__ logits, float* __restrict__ att)
{
    const int t = threadIdx.x, wave = t >> 6, lane = t & 63;
    const int g = blockIdx.x * 4 + wave;
    const float v = logits[g * 64 + lane];
    float m = v;
#pragma unroll
    for (int off = 32; off; off >>= 1) m = fmaxf(m, __shfl_xor(m, off, 64));
    const float e = __expf(v - m);
    float s = e;
#pragma unroll
    for (int off = 32; off; off >>= 1) s += __shfl_xor(s, off, 64);
    att[g * 64 + lane] = e / s;
}

// ---------------- pooling: weighted sum + pos ----------------
__global__ __launch_bounds__(256)
void pooled_kernel(const float* __restrict__ x, const float* __restrict__ att,
                   const float* __restrict__ pos, float* __restrict__ h,
                   bf16* __restrict__ hb, bf16* __restrict__ memb,
                   float* __restrict__ memf)
{
    __shared__ float sa[UU];
    const int t = threadIdx.x;
    const int bl = blockIdx.x >> 1, half = blockIdx.x & 1;
    const int l = bl & (LL - 1);
    const int d0 = half * 768;
    if (t < UU) sa[t] = att[bl * UU + t];
    __syncthreads();
    const float* xb = x + (size_t)bl * UU * D_MODEL + d0;
    float a0 = 0.f, a1 = 0.f, a2 = 0.f;
#pragma unroll 4
    for (int u = 0; u < UU; ++u) {
        const float p = sa[u];
        const float* xu = xb + (size_t)u * D_MODEL;
        a0 += p * xu[t];
        a1 += p * xu[t + 256];
        a2 += p * xu[t + 512];
    }
    const size_t db = (size_t)bl * D_MODEL + d0;
    const int pp = l * D_MODEL + d0;
    const float v0 = a0 + pos[pp + t];
    const float v1 = a1 + pos[pp + t + 256];
    const float v2 = a2 + pos[pp + t + 512];
    h[db + t] = v0; h[db + t + 256] = v1; h[db + t + 512] = v2;
    if (hb)   { hb[db + t] = (bf16)v0; hb[db + t + 256] = (bf16)v1; hb[db + t + 512] = (bf16)v2; }
    if (memb) { memb[db + t] = (bf16)v0; memb[db + t + 256] = (bf16)v1; memb[db + t + 512] = (bf16)v2; }
    if (memf) { memf[db + t] = v0; memf[db + t + 256] = v1; memf[db + t + 512] = v2; }
}

// ---------------- bf16 GEMM: C = A(M,K) @ W(N,K)^T + bias ----------------
// BM=64, BN=128, BK=64; global_load_lds staging, pre-swizzled source,
// XOR-swizzled LDS (granule ^ (row&7)) -> 2-way-max ds_read_b128 conflicts.
#define GBM 64
#define GBN 128

template<int MODE>  // 0: fp32 out C; 1: relu + bf16 out Cb
__global__ __launch_bounds__(256, 2)
void gemm_bf16_kernel(const bf16* __restrict__ A, const bf16* __restrict__ W,
                      const float* __restrict__ bias, float* __restrict__ C,
                      bf16* __restrict__ Cb, int M, int N, int K)
{
    __shared__ bf16 As[GBM * 64];
    __shared__ bf16 Bs[GBN * 64];
    const int t = threadIdx.x, wave = t >> 6, lane = t & 63;
    const int m0 = blockIdx.y * GBM, n0 = blockIdx.x * GBN;
    const int wr = wave >> 1, wc = wave & 1;
    const int frow = lane & 15, kq = lane >> 4, s = frow & 7;
    const int lr = lane >> 3;
    const int g8 = ((lane & 7) ^ lr) * 8;   // pre-swizzled source granule (elems)

    f32x4_t acc[2][4] = {};

    const bf16* Abase = A + (size_t)(m0 + wave * 8 + lr) * K + g8;
    const bf16* Wbase = W + (size_t)(n0 + wave * 8 + lr) * K + g8;
    bf16* AsW = As + wave * 512;
    bf16* BsW = Bs + wave * 512;

    for (int k0 = 0; k0 < K; k0 += 64) {
#pragma unroll
        for (int i = 0; i < 2; ++i)
            gload_lds16(Abase + k0 + (size_t)(i * 32) * K, AsW + i * 2048);
#pragma unroll
        for (int i = 0; i < 4; ++i)
            gload_lds16(Wbase + k0 + (size_t)(i * 32) * K, BsW + i * 2048);
        __syncthreads();
#pragma unroll
        for (int kk = 0; kk < 2; ++kk) {
            const int gg = (((kk << 2) | kq) ^ s) * 8;
            bf16x8_t af[2], bv[4];
#pragma unroll
            for (int mi = 0; mi < 2; ++mi)
                af[mi] = *(const bf16x8_t*)&As[(wr * 32 + mi * 16 + frow) * 64 + gg];
#pragma unroll
            for (int ni = 0; ni < 4; ++ni)
                bv[ni] = *(const bf16x8_t*)&Bs[(wc * 64 + ni * 16 + frow) * 64 + gg];
#pragma unroll
            for (int mi = 0; mi < 2; ++mi)
#pragma unroll
                for (int ni = 0; ni < 4; ++ni)
                    acc[mi][ni] = __builtin_amdgcn_mfma_f32_16x16x32_bf16(af[mi], bv[ni], acc[mi][ni], 0, 0, 0);
        }
        __syncthreads();
    }

    const int crow = m0 + wr * 32 + kq * 4;
    const int ccol = n0 + wc * 64 + frow;
#pragma unroll
    for (int mi = 0; mi < 2; ++mi)
#pragma unroll
        for (int ni = 0; ni < 4; ++ni) {
            const int col = ccol + ni * 16;
            const float bvv = bias[col];
            const int rb = crow + mi * 16;
#pragma unroll
            for (int j = 0; j < 4; ++j) {
                float v = acc[mi][ni][j] + bvv;
                if (MODE == 1) {
                    v = fmaxf(v, 0.f);
                    Cb[(size_t)(rb + j) * N + col] = (bf16)v;
                } else {
                    C[(size_t)(rb + j) * N + col] = v;
                }
            }
        }
}

// ---------------- fallback fp32-input GEMM (round-0, known-good) ----------
#define BM 128
#define BN 128
#define BKK 32
#define LDT 72

__global__ __launch_bounds__(256, 2)
void gemm_kernel(const float* __restrict__ A, const float* __restrict__ W,
                 const float* __restrict__ bias, float* __restrict__ C,
                 int M, int N, int K, int relu)
{
    __shared__ bf16 As[BM * LDT];
    __shared__ bf16 Bs[BN * LDT];
    const int t = threadIdx.x;
    const int wave = t >> 6, lane = t & 63;
    const int n0 = blockIdx.x * BN, m0 = blockIdx.y * BM;
    const int wr = wave >> 1, wc = wave & 1;
    const int frow = lane & 15, kb = lane >> 4;

    f32x4_t acc[4][4] = {};

    for (int k0 = 0; k0 < K; k0 += BKK) {
#pragma unroll
        for (int i = 0; i < 4; ++i) {
            const int idx = t + i * 256;
            const int r = idx >> 3, c4 = idx & 7;
            const float4 av = *(const float4*)(A + (size_t)(m0 + r) * K + k0 + c4 * 4);
            bf16x4_t a4 = { (bf16)av.x, (bf16)av.y, (bf16)av.z, (bf16)av.w };
            *(bf16x4_t*)(&As[r * LDT + c4 * 4]) = a4;
            const float4 wv = *(const float4*)(W + (size_t)(n0 + r) * K + k0 + c4 * 4);
            bf16x4_t b4 = { (bf16)wv.x, (bf16)wv.y, (bf16)wv.z, (bf16)wv.w };
            *(bf16x4_t*)(&Bs[r * LDT + c4 * 4]) = b4;
        }
        __syncthreads();
        bf16x8_t af[4], bfr[4];
#pragma unroll
        for (int mi = 0; mi < 4; ++mi)
            af[mi] = *(const bf16x8_t*)(&As[(wr * 64 + mi * 16 + frow) * LDT + kb * 8]);
#pragma unroll
        for (int ni = 0; ni < 4; ++ni)
            bfr[ni] = *(const bf16x8_t*)(&Bs[(wc * 64 + ni * 16 + frow) * LDT + kb * 8]);
#pragma unroll
        for (int mi = 0; mi < 4; ++mi)
#pragma unroll
            for (int ni = 0; ni < 4; ++ni)
                acc[mi][ni] = __builtin_amdgcn_mfma_f32_16x16x32_bf16(af[mi], bfr[ni], acc[mi][ni], 0, 0, 0);
        __syncthreads();
    }

    const int crow = m0 + wr * 64 + (lane >> 4) * 4;
    const int ccol = n0 + wc * 64 + (lane & 15);
#pragma unroll
    for (int mi = 0; mi < 4; ++mi)
#pragma unroll
        for (int ni = 0; ni < 4; ++ni) {
            const int col = ccol + ni * 16;
            const float bv = bias[col];
            const int rb = crow + mi * 16;
#pragma unroll
            for (int j = 0; j < 4; ++j) {
                float v = acc[mi][ni][j] + bv;
                if (relu) v = fmaxf(v, 0.f);
                C[(size_t)(rb + j) * N + col] = v;
            }
        }
}

// ---------------- attention core (per b,h block) ----------------
template<bool CAUSAL, bool BOUT>
__global__ __launch_bounds__(256)
void attn_kernel(const float* __restrict__ qbuf, int qstride, int qoff0,
                 const float* __restrict__ kbuf, int kstride, int koff0,
                 const float* __restrict__ vbuf, int vstride, int voff0,
                 void* __restrict__ outv)
{
    __shared__ float kv[HD * 64];
    __shared__ float sc[64 * 64];
    const int t = threadIdx.x, wave = t >> 6, lane = t & 63;
    const int b = blockIdx.x >> 3, hh = blockIdx.x & 7;
    const int t0 = b * 64;
    const float scale = rsqrtf((float)HD);

    for (int i = 0; i < 48; ++i) {
        const int idx = t + i * 256;
        const int r = idx / HD, c = idx % HD;
        kv[c * 64 + (r ^ (c & 31))] = kbuf[(size_t)(t0 + r) * kstride + koff0 + hh * HD + c];
    }
    __syncthreads();

    for (int qi = 0; qi < 16; ++qi) {
        const int q = wave * 16 + qi;
        const float* qr = qbuf + (size_t)(t0 + q) * qstride + qoff0 + hh * HD;
        float a = 0.f;
#pragma unroll 8
        for (int d = 0; d < HD; ++d)
            a += qr[d] * kv[d * 64 + (lane ^ (d & 31))];
        a *= scale;
        if (CAUSAL && lane > q) a = -__builtin_inff();
        float m = a;
#pragma unroll
        for (int off = 32; off; off >>= 1) m = fmaxf(m, __shfl_xor(m, off, 64));
        float e = (CAUSAL && lane > q) ? 0.f : __expf(a - m);
        float s = e;
#pragma unroll
        for (int off = 32; off; off >>= 1) s += __shfl_xor(s, off, 64);
        sc[q * 64 + lane] = e / s;
    }
    __syncthreads();

    for (int i = 0; i < 48; ++i) {
        const int idx = t + i * 256;
        const int r = idx / HD, c = idx % HD;
        kv[r * HD + c] = vbuf[(size_t)(t0 + r) * vstride + voff0 + hh * HD + c];
    }
    __syncthreads();

    for (int qi = 0; qi < 16; ++qi) {
        const int q = wave * 16 + qi;
        float o0 = 0.f, o1 = 0.f, o2 = 0.f;
#pragma unroll 8
        for (int k = 0; k < 64; ++k) {
            const float p = sc[q * 64 + k];
            o0 += p * kv[k * HD + lane];
            o1 += p * kv[k * HD + 64 + lane];
            o2 += p * kv[k * HD + 128 + lane];
        }
        const size_t ob = (size_t)(t0 + q) * D_MODEL + hh * HD;
        if (BOUT) {
            bf16* op = (bf16*)outv + ob;
            op[lane] = (bf16)o0; op[64 + lane] = (bf16)o1; op[128 + lane] = (bf16)o2;
        } else {
            float* op = (float*)outv + ob;
            op[lane] = o0; op[64 + lane] = o1; op[128 + lane] = o2;
        }
    }
}

// ---------------- residual + LayerNorm ----------------
template<bool WB>
__global__ __launch_bounds__(256)
void ln_kernel(const float* __restrict__ a, const float* __restrict__ r,
               const float* __restrict__ w, const float* __restrict__ bb,
               float* __restrict__ out, bf16* __restrict__ outb)
{
    __shared__ float red[8];
    const int tok = blockIdx.x, t = threadIdx.x;
    const int wave = t >> 6, lane = t & 63;
    const float* ap = a + (size_t)tok * D_MODEL;
    const float* rp = r + (size_t)tok * D_MODEL;
    float v[6];
    float s = 0.f;
#pragma unroll
    for (int j = 0; j < 6; ++j) { v[j] = ap[t + j * 256] + rp[t + j * 256]; s += v[j]; }
#pragma unroll
    for (int off = 32; off; off >>= 1) s += __shfl_xor(s, off, 64);
    if (lane == 0) red[wave] = s;
    __syncthreads();
    const float mu = (red[0] + red[1] + red[2] + red[3]) * (1.f / D_MODEL);
    float s2 = 0.f;
#pragma unroll
    for (int j = 0; j < 6; ++j) { const float d = v[j] - mu; s2 += d * d; }
#pragma unroll
    for (int off = 32; off; off >>= 1) s2 += __shfl_xor(s2, off, 64);
    if (lane == 0) red[4 + wave] = s2;
    __syncthreads();
    const float var = (red[4] + red[5] + red[6] + red[7]) * (1.f / D_MODEL);
    const float inv = rsqrtf(var + EPSF);
#pragma unroll
    for (int j = 0; j < 6; ++j) {
        const int d = t + j * 256;
        const float o = (v[j] - mu) * inv * w[d] + bb[d];
        out[(size_t)tok * D_MODEL + d] = o;
        if (WB) outb[(size_t)tok * D_MODEL + d] = (bf16)o;
    }
}

// ---------------- output slice h[:, :63, :] ----------------
__global__ __launch_bounds__(256)
void slice_kernel(const float* __restrict__ h, float* __restrict__ out)
{
    const int i = blockIdx.x * 256 + threadIdx.x;
    if (i >= BB * 63 * (D_MODEL / 4)) return;
    const int d4 = i % (D_MODEL / 4);
    const int tl = i / (D_MODEL / 4);
    const int b = tl / 63, l = tl % 63;
    ((float4*)out)[i] = ((const float4*)(h + (size_t)(b * 64 + l) * D_MODEL))[d4];
}

extern "C" void kernel_launch(void* const* d_in, const int* in_sizes, int n_in,
                              void* d_out, int out_size, void* d_ws, size_t ws_size,
                              hipStream_t stream)
{
    (void)in_sizes; (void)n_in; (void)out_size;
    const float* x        = (const float*)d_in[0];
    const float* pooler_w = (const float*)d_in[1];
    const float* pooler_b = (const float*)d_in[2];
    const float* pos      = (const float*)d_in[3];
    const float* sa_qkv_w = (const float*)d_in[4];
    const float* sa_qkv_b = (const float*)d_in[5];
    const float* sa_out_w = (const float*)d_in[6];
    const float* sa_out_b = (const float*)d_in[7];
    const float* ca_qkv_w = (const float*)d_in[8];
    const float* ca_qkv_b = (const float*)d_in[9];
    const float* ca_out_w = (const float*)d_in[10];
    const float* ca_out_b = (const float*)d_in[11];
    const float* ff1_w    = (const float*)d_in[12];
    const float* ff1_b    = (const float*)d_in[13];
    const float* ff2_w    = (const float*)d_in[14];
    const float* ff2_b    = (const float*)d_in[15];
    const float* ln1_w    = (const float*)d_in[16];
    const float* ln1_b    = (const float*)d_in[17];
    const float* ln2_w    = (const float*)d_in[18];
    const float* ln2_b    = (const float*)d_in[19];
    const float* ln3_w    = (const float*)d_in[20];
    const float* ln3_b    = (const float*)d_in[21];
    float* outp = (float*)d_out;

    // ---------- new-path workspace layout ----------
    char* ws = (char*)d_ws;
    size_t off = 0;
    auto alloc = [&](size_t bytes) { char* p = ws + off; off += (bytes + 255) & ~(size_t)255; return p; };

    const size_t E_QKV = (size_t)4608 * D_MODEL;       // per layer elems
    const size_t E_SQ  = (size_t)D_MODEL * D_MODEL;
    const size_t E_F1  = (size_t)2048 * D_MODEL;

    bf16* wb_sa_qkv = (bf16*)alloc(2 * E_QKV * 2);
    bf16* wb_sa_out = (bf16*)alloc(2 * E_SQ * 2);
    bf16* wb_ca_qkv = (bf16*)alloc(2 * E_QKV * 2);
    bf16* wb_ca_out = (bf16*)alloc(2 * E_SQ * 2);
    bf16* wb_ff1    = (bf16*)alloc(2 * E_F1 * 2);
    bf16* wb_ff2    = (bf16*)alloc(2 * E_F1 * 2);
    float* h     = (float*)alloc((size_t)NTOK * D_MODEL * 4);
    bf16*  hb    = (bf16*) alloc((size_t)NTOK * D_MODEL * 2);
    bf16*  memb  = (bf16*) alloc((size_t)NTOK * D_MODEL * 2);
    float* qkv   = (float*)alloc((size_t)NTOK * 4608 * 4);
    bf16*  attno = (bf16*) alloc((size_t)NTOK * D_MODEL * 2);
    float* proj  = (float*)alloc((size_t)NTOK * D_MODEL * 4);
    bf16*  ffmid = (bf16*) alloc((size_t)NTOK * 2048 * 2);
    const size_t need_new = off;

    if (ws_size >= need_new) {
        // aliases into qkv region (free until first GEMM)
        float* logits = qkv;
        float* att    = qkv + 65536;
        float* cq     = qkv;                          // free after self-attn
        float* ckv    = qkv + (size_t)NTOK * D_MODEL;

        cvt_kernel<<<1024, 256, 0, stream>>>(sa_qkv_w, wb_sa_qkv, (int)(2 * E_QKV / 4));
        cvt_kernel<<<512,  256, 0, stream>>>(sa_out_w, wb_sa_out, (int)(2 * E_SQ  / 4));
        cvt_kernel<<<1024, 256, 0, stream>>>(ca_qkv_w, wb_ca_qkv, (int)(2 * E_QKV / 4));
        cvt_kernel<<<512,  256, 0, stream>>>(ca_out_w, wb_ca_out, (int)(2 * E_SQ  / 4));
        cvt_kernel<<<512,  256, 0, stream>>>(ff1_w,    wb_ff1,    (int)(2 * E_F1  / 4));
        cvt_kernel<<<512,  256, 0, stream>>>(ff2_w,    wb_ff2,    (int)(2 * E_F1  / 4));

        logits_kernel  <<<4096, 256, 0, stream>>>(x, pooler_w, pooler_b, logits);
        usoftmax_kernel<<<256,  256, 0, stream>>>(logits, att);
        pooled_kernel  <<<2048, 256, 0, stream>>>(x, att, pos, h, hb, memb, nullptr);

        for (int i = 0; i < 2; ++i) {
            gemm_bf16_kernel<0><<<dim3(36, 16), 256, 0, stream>>>(
                hb, wb_sa_qkv + (size_t)i * E_QKV, sa_qkv_b + (size_t)i * 4608,
                qkv, nullptr, NTOK, 4608, D_MODEL);
            attn_kernel<true, true><<<BB * NH, 256, 0, stream>>>(
                qkv, 4608, 0, qkv, 4608, 1536, qkv, 4608, 3072, attno);
            gemm_bf16_kernel<0><<<dim3(12, 16), 256, 0, stream>>>(
                attno, wb_sa_out + (size_t)i * E_SQ, sa_out_b + (size_t)i * D_MODEL,
                proj, nullptr, NTOK, D_MODEL, D_MODEL);
            ln_kernel<true><<<NTOK, 256, 0, stream>>>(h, proj, ln1_w + i * D_MODEL, ln1_b + i * D_MODEL, h, hb);

            gemm_bf16_kernel<0><<<dim3(12, 16), 256, 0, stream>>>(
                hb, wb_ca_qkv + (size_t)i * E_QKV, ca_qkv_b + (size_t)i * 4608,
                cq, nullptr, NTOK, D_MODEL, D_MODEL);
            gemm_bf16_kernel<0><<<dim3(24, 16), 256, 0, stream>>>(
                memb, wb_ca_qkv + (size_t)i * E_QKV + (size_t)1536 * D_MODEL,
                ca_qkv_b + (size_t)i * 4608 + 1536,
                ckv, nullptr, NTOK, 3072, D_MODEL);
            attn_kernel<false, true><<<BB * NH, 256, 0, stream>>>(
                cq, 1536, 0, ckv, 3072, 0, ckv, 3072, 1536, attno);
            gemm_bf16_kernel<0><<<dim3(12, 16), 256, 0, stream>>>(
                attno, wb_ca_out + (size_t)i * E_SQ, ca_out_b + (size_t)i * D_MODEL,
                proj, nullptr, NTOK, D_MODEL, D_MODEL);
            ln_kernel<true><<<NTOK, 256, 0, stream>>>(h, proj, ln2_w + i * D_MODEL, ln2_b + i * D_MODEL, h, hb);

            gemm_bf16_kernel<1><<<dim3(16, 16), 256, 0, stream>>>(
                hb, wb_ff1 + (size_t)i * E_F1, ff1_b + (size_t)i * 2048,
                nullptr, ffmid, NTOK, 2048, D_MODEL);
            gemm_bf16_kernel<0><<<dim3(12, 16), 256, 0, stream>>>(
                ffmid, wb_ff2 + (size_t)i * E_F1, ff2_b + (size_t)i * D_MODEL,
                proj, nullptr, NTOK, D_MODEL, 2048);
            ln_kernel<true><<<NTOK, 256, 0, stream>>>(h, proj, ln3_w + i * D_MODEL, ln3_b + i * D_MODEL, h, hb);
        }

        slice_kernel<<<(BB * 63 * (D_MODEL / 4) + 255) / 256, 256, 0, stream>>>(h, outp);
        return;
    }

    // ---------- fallback: round-0 fp32 path ----------
    float* wsf   = (float*)d_ws;
    float* memF  = wsf;
    float* hF    = memF  + (size_t)NTOK * D_MODEL;
    float* qkvF  = hF    + (size_t)NTOK * D_MODEL;
    float* attnoF= qkvF  + (size_t)NTOK * 4608;
    float* projF = attnoF+ (size_t)NTOK * D_MODEL;
    float* ffmidF= projF + (size_t)NTOK * D_MODEL;
    float* ckvF  = ffmidF+ (size_t)NTOK * 2048;
    float* cqF   = ckvF  + (size_t)NTOK * 3072;
    float* logitsF = qkvF;
    float* attF    = qkvF + 65536;

    logits_kernel  <<<4096, 256, 0, stream>>>(x, pooler_w, pooler_b, logitsF);
    usoftmax_kernel<<<256,  256, 0, stream>>>(logitsF, attF);
    pooled_kernel  <<<2048, 256, 0, stream>>>(x, attF, pos, hF, nullptr, nullptr, memF);

    for (int i = 0; i < 2; ++i) {
        gemm_kernel<<<dim3(36, 8), 256, 0, stream>>>(
            hF, sa_qkv_w + (size_t)i * 4608 * D_MODEL, sa_qkv_b + (size_t)i * 4608,
            qkvF, NTOK, 4608, D_MODEL, 0);
        attn_kernel<true, false><<<BB * NH, 256, 0, stream>>>(
            qkvF, 4608, 0, qkvF, 4608, 1536, qkvF, 4608, 3072, attnoF);
        gemm_kernel<<<dim3(12, 8), 256, 0, stream>>>(
            attnoF, sa_out_w + (size_t)i * D_MODEL * D_MODEL, sa_out_b + (size_t)i * D_MODEL,
            projF, NTOK, D_MODEL, D_MODEL, 0);
        ln_kernel<false><<<NTOK, 256, 0, stream>>>(hF, projF, ln1_w + i * D_MODEL, ln1_b + i * D_MODEL, hF, nullptr);

        gemm_kernel<<<dim3(12, 8), 256, 0, stream>>>(
            hF, ca_qkv_w + (size_t)i * 4608 * D_MODEL, ca_qkv_b + (size_t)i * 4608,
            cqF, NTOK, D_MODEL, D_MODEL, 0);
        gemm_kernel<<<dim3(24, 8), 256, 0, stream>>>(
            memF, ca_qkv_w + (size_t)i * 4608 * D_MODEL + (size_t)1536 * D_MODEL,
            ca_qkv_b + (size_t)i * 4608 + 1536,
            ckvF, NTOK, 3072, D_MODEL, 0);
        attn_kernel<false, false><<<BB * NH, 256, 0, stream>>>(
            cqF, 1536, 0, ckvF, 3072, 0, ckvF, 3072, 1536, attnoF);
        gemm_kernel<<<dim3(12, 8), 256, 0, stream>>>(
            attnoF, ca_out_w + (size_t)i * D_MODEL * D_MODEL, ca_out_b + (size_t)i * D_MODEL,
            projF, NTOK, D_MODEL, D_MODEL, 0);
        ln_kernel<false><<<NTOK, 256, 0, stream>>>(hF, projF, ln2_w + i * D_MODEL, ln2_b + i * D_MODEL, hF, nullptr);

        gemm_kernel<<<dim3(16, 8), 256, 0, stream>>>(
            hF, ff1_w + (size_t)i * 2048 * D_MODEL, ff1_b + (size_t)i * 2048,
            ffmidF, NTOK, 2048, D_MODEL, 1);
        gemm_kernel<<<dim3(12, 8), 256, 0, stream>>>(
            ffmidF, ff2_w + (size_t)i * D_MODEL * 2048, ff2_b + (size_t)i * D_MODEL,
            projF, NTOK, D_MODEL, 2048, 0);
        ln_kernel<false><<<NTOK, 256, 0, stream>>>(hF, projF, ln3_w + i * D_MODEL, ln3_b + i * D_MODEL, hF, nullptr);
    }

    slice_kernel<<<(BB * 63 * (D_MODEL / 4) + 255) / 256, 256, 0, stream>>>(hF, outp);
}

// Round 3
// 1063.995 us; speedup vs baseline: 1.6275x; 1.0147x over previous
//
#include <hip/hip_runtime.h>
#include <math.h>

#define D_MODEL 1536
#define NH      8
#define HD      192
#define BB      16
#define LL      64
#define UU      64
#define NTOK    1024
#define EPSF    1e-5f

typedef __bf16 bf16;
typedef __bf16 bf16x4_t __attribute__((ext_vector_type(4)));
typedef __bf16 bf16x8_t __attribute__((ext_vector_type(8)));
typedef float  f32x4_t  __attribute__((ext_vector_type(4)));

__device__ __forceinline__ void gload_lds16(const bf16* g, bf16* l) {
    __builtin_amdgcn_global_load_lds((const __attribute__((address_space(1))) void*)g,
                                     (__attribute__((address_space(3))) void*)l, 16, 0, 0);
}

// ---------------- weight fp32 -> bf16 convert ----------------
__global__ __launch_bounds__(256)
void cvt_kernel(const float* __restrict__ s, bf16* __restrict__ d, int n4)
{
    int i = blockIdx.x * 256 + threadIdx.x;
    const int stride = gridDim.x * 256;
    for (; i < n4; i += stride) {
        const float4 v = ((const float4*)s)[i];
        bf16x4_t o = { (bf16)v.x, (bf16)v.y, (bf16)v.z, (bf16)v.w };
        ((bf16x4_t*)d)[i] = o;
    }
}

// ---------------- fused pooling: softmax(x@pw) @ x + pos, one x pass ------
__global__ __launch_bounds__(256)
void fusedpool_kernel(const float* __restrict__ x, const float* __restrict__ pw,
                      const float* __restrict__ pb, const float* __restrict__ pos,
                      float* __restrict__ h, bf16* __restrict__ hb,
                      bf16* __restrict__ memb, float* __restrict__ memf)
{
    __shared__ float red[2][4];
    const int t = threadIdx.x, wave = t >> 6, lane = t & 63;
    const int bl = blockIdx.x, l = bl & (LL - 1);
    const float* xb = x + (size_t)bl * UU * D_MODEL;

    float pwr[6];
#pragma unroll
    for (int j = 0; j < 6; ++j) pwr[j] = pw[t + j * 256];
    const float pb0 = pb[0];

    float xv[2][6];
#pragma unroll
    for (int j = 0; j < 6; ++j) xv[0][j] = xb[t + j * 256];

    float m = -__builtin_inff(), den = 0.f;
    float acc[6] = {0.f, 0.f, 0.f, 0.f, 0.f, 0.f};

    for (int u = 0; u < UU; ++u) {
        const int cur = u & 1;
        if (u < UU - 1) {
            const float* xn = xb + (size_t)(u + 1) * D_MODEL;
#pragma unroll
            for (int j = 0; j < 6; ++j) xv[cur ^ 1][j] = xn[t + j * 256];
        }
        float p = 0.f;
#pragma unroll
        for (int j = 0; j < 6; ++j) p += xv[cur][j] * pwr[j];
#pragma unroll
        for (int off = 32; off; off >>= 1) p += __shfl_xor(p, off, 64);
        if (lane == 0) red[cur][wave] = p;
        __syncthreads();
        const float logit = red[cur][0] + red[cur][1] + red[cur][2] + red[cur][3] + pb0;
        const float nm = fmaxf(m, logit);
        const float sc = __expf(m - nm);      // first iter: exp(-inf)=0
        const float w  = __expf(logit - nm);
#pragma unroll
        for (int j = 0; j < 6; ++j) acc[j] = acc[j] * sc + w * xv[cur][j];
        den = den * sc + w;
        m = nm;
    }

    const float inv = 1.f / den;
    const size_t db = (size_t)bl * D_MODEL;
    const int pp = l * D_MODEL;
#pragma unroll
    for (int j = 0; j < 6; ++j) {
        const int d = t + j * 256;
        const float v = acc[j] * inv + pos[pp + d];
        if (h)    h[db + d] = v;
        if (hb)   hb[db + d] = (bf16)v;
        if (memb) memb[db + d] = (bf16)v;
        if (memf) memf[db + d] = v;
    }
}

// ---------------- bf16 GEMM: C = A(M,K) @ W(N,K)^T + bias ----------------
// BM=64, BN=128, BK=64; global_load_lds staging, pre-swizzled source,
// XOR-swizzled LDS; 1D grid + XCD-chunked swizzle (each XCD owns a
// contiguous n-tile chunk, m fastest within chunk -> W panels L2-resident).
#define GBM 64
#define GBN 128

template<int MODE>  // 0: fp32 out C; 1: relu + bf16 out Cb
__global__ __launch_bounds__(256, 3)
void gemm_bf16_kernel(const bf16* __restrict__ A, const bf16* __restrict__ W,
                      const float* __restrict__ bias, float* __restrict__ C,
                      bf16* __restrict__ Cb, int M, int N, int K)
{
    __shared__ bf16 As[GBM * 64];
    __shared__ bf16 Bs[GBN * 64];
    const int t = threadIdx.x, wave = t >> 6, lane = t & 63;

    // XCD-chunked bijective swizzle (T multiple of 8 since M/GBM == 16)
    const int T = gridDim.x;
    const int fid = blockIdx.x;
    const int vid = (fid & 7) * (T >> 3) + (fid >> 3);
    const int m0 = (vid & 15) * GBM;       // M/GBM == 16 always (M=1024)
    const int n0 = (vid >> 4) * GBN;

    const int wr = wave >> 1, wc = wave & 1;
    const int frow = lane & 15, kq = lane >> 4, s = frow & 7;
    const int lr = lane >> 3;
    const int g8 = ((lane & 7) ^ lr) * 8;   // pre-swizzled source granule (elems)

    f32x4_t acc[2][4] = {};

    const bf16* Abase = A + (size_t)(m0 + wave * 8 + lr) * K + g8;
    const bf16* Wbase = W + (size_t)(n0 + wave * 8 + lr) * K + g8;
    bf16* AsW = As + wave * 512;
    bf16* BsW = Bs + wave * 512;

    for (int k0 = 0; k0 < K; k0 += 64) {
#pragma unroll
        for (int i = 0; i < 2; ++i)
            gload_lds16(Abase + k0 + (size_t)(i * 32) * K, AsW + i * 2048);
#pragma unroll
        for (int i = 0; i < 4; ++i)
            gload_lds16(Wbase + k0 + (size_t)(i * 32) * K, BsW + i * 2048);
        __syncthreads();
#pragma unroll
        for (int kk = 0; kk < 2; ++kk) {
            const int gg = (((kk << 2) | kq) ^ s) * 8;
            bf16x8_t af[2], bv[4];
#pragma unroll
            for (int mi = 0; mi < 2; ++mi)
                af[mi] = *(const bf16x8_t*)&As[(wr * 32 + mi * 16 + frow) * 64 + gg];
#pragma unroll
            for (int ni = 0; ni < 4; ++ni)
                bv[ni] = *(const bf16x8_t*)&Bs[(wc * 64 + ni * 16 + frow) * 64 + gg];
#pragma unroll
            for (int mi = 0; mi < 2; ++mi)
#pragma unroll
                for (int ni = 0; ni < 4; ++ni)
                    acc[mi][ni] = __builtin_amdgcn_mfma_f32_16x16x32_bf16(af[mi], bv[ni], acc[mi][ni], 0, 0, 0);
        }
        __syncthreads();
    }

    const int crow = m0 + wr * 32 + kq * 4;
    const int ccol = n0 + wc * 64 + frow;
#pragma unroll
    for (int mi = 0; mi < 2; ++mi)
#pragma unroll
        for (int ni = 0; ni < 4; ++ni) {
            const int col = ccol + ni * 16;
            const float bvv = bias[col];
            const int rb = crow + mi * 16;
#pragma unroll
            for (int j = 0; j < 4; ++j) {
                float v = acc[mi][ni][j] + bvv;
                if (MODE == 1) {
                    v = fmaxf(v, 0.f);
                    Cb[(size_t)(rb + j) * N + col] = (bf16)v;
                } else {
                    C[(size_t)(rb + j) * N + col] = v;
                }
            }
        }
}

// ---------------- fallback fp32-input GEMM (round-0, known-good) ----------
#define BM 128
#define BN 128
#define BKK 32
#define LDT 72

__global__ __launch_bounds__(256, 2)
void gemm_kernel(const float* __restrict__ A, const float* __restrict__ W,
                 const float* __restrict__ bias, float* __restrict__ C,
                 int M, int N, int K, int relu)
{
    __shared__ bf16 As[BM * LDT];
    __shared__ bf16 Bs[BN * LDT];
    const int t = threadIdx.x;
    const int wave = t >> 6, lane = t & 63;
    const int n0 = blockIdx.x * BN, m0 = blockIdx.y * BM;
    const int wr = wave >> 1, wc = wave & 1;
    const int frow = lane & 15, kb = lane >> 4;

    f32x4_t acc[4][4] = {};

    for (int k0 = 0; k0 < K; k0 += BKK) {
#pragma unroll
        for (int i = 0; i < 4; ++i) {
            const int idx = t + i * 256;
            const int r = idx >> 3, c4 = idx & 7;
            const float4 av = *(const float4*)(A + (size_t)(m0 + r) * K + k0 + c4 * 4);
            bf16x4_t a4 = { (bf16)av.x, (bf16)av.y, (bf16)av.z, (bf16)av.w };
            *(bf16x4_t*)(&As[r * LDT + c4 * 4]) = a4;
            const float4 wv = *(const float4*)(W + (size_t)(n0 + r) * K + k0 + c4 * 4);
            bf16x4_t b4 = { (bf16)wv.x, (bf16)wv.y, (bf16)wv.z, (bf16)wv.w };
            *(bf16x4_t*)(&Bs[r * LDT + c4 * 4]) = b4;
        }
        __syncthreads();
        bf16x8_t af[4], bfr[4];
#pragma unroll
        for (int mi = 0; mi < 4; ++mi)
            af[mi] = *(const bf16x8_t*)(&As[(wr * 64 + mi * 16 + frow) * LDT + kb * 8]);
#pragma unroll
        for (int ni = 0; ni < 4; ++ni)
            bfr[ni] = *(const bf16x8_t*)(&Bs[(wc * 64 + ni * 16 + frow) * LDT + kb * 8]);
#pragma unroll
        for (int mi = 0; mi < 4; ++mi)
#pragma unroll
            for (int ni = 0; ni < 4; ++ni)
                acc[mi][ni] = __builtin_amdgcn_mfma_f32_16x16x32_bf16(af[mi], bfr[ni], acc[mi][ni], 0, 0, 0);
        __syncthreads();
    }

    const int crow = m0 + wr * 64 + (lane >> 4) * 4;
    const int ccol = n0 + wc * 64 + (lane & 15);
#pragma unroll
    for (int mi = 0; mi < 4; ++mi)
#pragma unroll
        for (int ni = 0; ni < 4; ++ni) {
            const int col = ccol + ni * 16;
            const float bv = bias[col];
            const int rb = crow + mi * 16;
#pragma unroll
            for (int j = 0; j < 4; ++j) {
                float v = acc[mi][ni][j] + bv;
                if (relu) v = fmaxf(v, 0.f);
                C[(size_t)(rb + j) * N + col] = v;
            }
        }
}

// ---------------- attention core (per b,h block) ----------------
template<bool CAUSAL, bool BOUT>
__global__ __launch_bounds__(256)
void attn_kernel(const float* __restrict__ qbuf, int qstride, int qoff0,
                 const float* __restrict__ kbuf, int kstride, int koff0,
                 const float* __restrict__ vbuf, int vstride, int voff0,
                 void* __restrict__ outv)
{
    __shared__ float kv[HD * 64];
    __shared__ float sc[64 * 64];
    const int t = threadIdx.x, wave = t >> 6, lane = t & 63;
    const int b = blockIdx.x >> 3, hh = blockIdx.x & 7;
    const int t0 = b * 64;
    const float scale = rsqrtf((float)HD);

    for (int i = 0; i < 48; ++i) {
        const int idx = t + i * 256;
        const int r = idx / HD, c = idx % HD;
        kv[c * 64 + (r ^ (c & 31))] = kbuf[(size_t)(t0 + r) * kstride + koff0 + hh * HD + c];
    }
    __syncthreads();

    for (int qi = 0; qi < 16; ++qi) {
        const int q = wave * 16 + qi;
        const float* qr = qbuf + (size_t)(t0 + q) * qstride + qoff0 + hh * HD;
        float a = 0.f;
#pragma unroll 8
        for (int d = 0; d < HD; ++d)
            a += qr[d] * kv[d * 64 + (lane ^ (d & 31))];
        a *= scale;
        if (CAUSAL && lane > q) a = -__builtin_inff();
        float m = a;
#pragma unroll
        for (int off = 32; off; off >>= 1) m = fmaxf(m, __shfl_xor(m, off, 64));
        float e = (CAUSAL && lane > q) ? 0.f : __expf(a - m);
        float s = e;
#pragma unroll
        for (int off = 32; off; off >>= 1) s += __shfl_xor(s, off, 64);
        sc[q * 64 + lane] = e / s;
    }
    __syncthreads();

    for (int i = 0; i < 48; ++i) {
        const int idx = t + i * 256;
        const int r = idx / HD, c = idx % HD;
        kv[r * HD + c] = vbuf[(size_t)(t0 + r) * vstride + voff0 + hh * HD + c];
    }
    __syncthreads();

    for (int qi = 0; qi < 16; ++qi) {
        const int q = wave * 16 + qi;
        float o0 = 0.f, o1 = 0.f, o2 = 0.f;
#pragma unroll 8
        for (int k = 0; k < 64; ++k) {
            const float p = sc[q * 64 + k];
            o0 += p * kv[k * HD + lane];
            o1 += p * kv[k * HD + 64 + lane];
            o2 += p * kv[k * HD + 128 + lane];
        }
        const size_t ob = (size_t)(t0 + q) * D_MODEL + hh * HD;
        if (BOUT) {
            bf16* op = (bf16*)outv + ob;
            op[lane] = (bf16)o0; op[64 + lane] = (bf16)o1; op[128 + lane] = (bf16)o2;
        } else {
            float* op = (float*)outv + ob;
            op[lane] = o0; op[64 + lane] = o1; op[128 + lane] = o2;
        }
    }
}

// ---------------- residual + LayerNorm ----------------
template<bool WB>
__global__ __launch_bounds__(256)
void ln_kernel(const float* __restrict__ a, const float* __restrict__ r,
               const float* __restrict__ w, const float* __restrict__ bb,
               float* __restrict__ out, bf16* __restrict__ outb)
{
    __shared__ float red[8];
    const int tok = blockIdx.x, t = threadIdx.x;
    const int wave = t >> 6, lane = t & 63;
    const float* ap = a + (size_t)tok * D_MODEL;
    const float* rp = r + (size_t)tok * D_MODEL;
    float v[6];
    float s = 0.f;
#pragma unroll
    for (int j = 0; j < 6; ++j) { v[j] = ap[t + j * 256] + rp[t + j * 256]; s += v[j]; }
#pragma unroll
    for (int off = 32; off; off >>= 1) s += __shfl_xor(s, off, 64);
    if (lane == 0) red[wave] = s;
    __syncthreads();
    const float mu = (red[0] + red[1] + red[2] + red[3]) * (1.f / D_MODEL);
    float s2 = 0.f;
#pragma unroll
    for (int j = 0; j < 6; ++j) { const float d = v[j] - mu; s2 += d * d; }
#pragma unroll
    for (int off = 32; off; off >>= 1) s2 += __shfl_xor(s2, off, 64);
    if (lane == 0) red[4 + wave] = s2;
    __syncthreads();
    const float var = (red[4] + red[5] + red[6] + red[7]) * (1.f / D_MODEL);
    const float inv = rsqrtf(var + EPSF);
#pragma unroll
    for (int j = 0; j < 6; ++j) {
        const int d = t + j * 256;
        const float o = (v[j] - mu) * inv * w[d] + bb[d];
        out[(size_t)tok * D_MODEL + d] = o;
        if (WB) outb[(size_t)tok * D_MODEL + d] = (bf16)o;
    }
}

// ---------------- output slice h[:, :63, :] ----------------
__global__ __launch_bounds__(256)
void slice_kernel(const float* __restrict__ h, float* __restrict__ out)
{
    const int i = blockIdx.x * 256 + threadIdx.x;
    if (i >= BB * 63 * (D_MODEL / 4)) return;
    const int d4 = i % (D_MODEL / 4);
    const int tl = i / (D_MODEL / 4);
    const int b = tl / 63, l = tl % 63;
    ((float4*)out)[i] = ((const float4*)(h + (size_t)(b * 64 + l) * D_MODEL))[d4];
}

extern "C" void kernel_launch(void* const* d_in, const int* in_sizes, int n_in,
                              void* d_out, int out_size, void* d_ws, size_t ws_size,
                              hipStream_t stream)
{
    (void)in_sizes; (void)n_in; (void)out_size;
    const float* x        = (const float*)d_in[0];
    const float* pooler_w = (const float*)d_in[1];
    const float* pooler_b = (const float*)d_in[2];
    const float* pos      = (const float*)d_in[3];
    const float* sa_qkv_w = (const float*)d_in[4];
    const float* sa_qkv_b = (const float*)d_in[5];
    const float* sa_out_w = (const float*)d_in[6];
    const float* sa_out_b = (const float*)d_in[7];
    const float* ca_qkv_w = (const float*)d_in[8];
    const float* ca_qkv_b = (const float*)d_in[9];
    const float* ca_out_w = (const float*)d_in[10];
    const float* ca_out_b = (const float*)d_in[11];
    const float* ff1_w    = (const float*)d_in[12];
    const float* ff1_b    = (const float*)d_in[13];
    const float* ff2_w    = (const float*)d_in[14];
    const float* ff2_b    = (const float*)d_in[15];
    const float* ln1_w    = (const float*)d_in[16];
    const float* ln1_b    = (const float*)d_in[17];
    const float* ln2_w    = (const float*)d_in[18];
    const float* ln2_b    = (const float*)d_in[19];
    const float* ln3_w    = (const float*)d_in[20];
    const float* ln3_b    = (const float*)d_in[21];
    float* outp = (float*)d_out;

    // ---------- new-path workspace layout ----------
    char* ws = (char*)d_ws;
    size_t off = 0;
    auto alloc = [&](size_t bytes) { char* p = ws + off; off += (bytes + 255) & ~(size_t)255; return p; };

    const size_t E_QKV = (size_t)4608 * D_MODEL;       // per layer elems
    const size_t E_SQ  = (size_t)D_MODEL * D_MODEL;
    const size_t E_F1  = (size_t)2048 * D_MODEL;

    bf16* wb_sa_qkv = (bf16*)alloc(2 * E_QKV * 2);
    bf16* wb_sa_out = (bf16*)alloc(2 * E_SQ * 2);
    bf16* wb_ca_qkv = (bf16*)alloc(2 * E_QKV * 2);
    bf16* wb_ca_out = (bf16*)alloc(2 * E_SQ * 2);
    bf16* wb_ff1    = (bf16*)alloc(2 * E_F1 * 2);
    bf16* wb_ff2    = (bf16*)alloc(2 * E_F1 * 2);
    float* h     = (float*)alloc((size_t)NTOK * D_MODEL * 4);
    bf16*  hb    = (bf16*) alloc((size_t)NTOK * D_MODEL * 2);
    bf16*  memb  = (bf16*) alloc((size_t)NTOK * D_MODEL * 2);
    float* qkv   = (float*)alloc((size_t)NTOK * 4608 * 4);
    bf16*  attno = (bf16*) alloc((size_t)NTOK * D_MODEL * 2);
    float* proj  = (float*)alloc((size_t)NTOK * D_MODEL * 4);
    bf16*  ffmid = (bf16*) alloc((size_t)NTOK * 2048 * 2);
    const size_t need_new = off;

    if (ws_size >= need_new) {
        float* cq  = qkv;                          // aliases, free outside attn
        float* ckv = qkv + (size_t)NTOK * D_MODEL;

        cvt_kernel<<<1024, 256, 0, stream>>>(sa_qkv_w, wb_sa_qkv, (int)(2 * E_QKV / 4));
        cvt_kernel<<<512,  256, 0, stream>>>(sa_out_w, wb_sa_out, (int)(2 * E_SQ  / 4));
        cvt_kernel<<<1024, 256, 0, stream>>>(ca_qkv_w, wb_ca_qkv, (int)(2 * E_QKV / 4));
        cvt_kernel<<<512,  256, 0, stream>>>(ca_out_w, wb_ca_out, (int)(2 * E_SQ  / 4));
        cvt_kernel<<<512,  256, 0, stream>>>(ff1_w,    wb_ff1,    (int)(2 * E_F1  / 4));
        cvt_kernel<<<512,  256, 0, stream>>>(ff2_w,    wb_ff2,    (int)(2 * E_F1  / 4));

        fusedpool_kernel<<<NTOK, 256, 0, stream>>>(x, pooler_w, pooler_b, pos,
                                                   h, hb, memb, nullptr);

        for (int i = 0; i < 2; ++i) {
            gemm_bf16_kernel<0><<<16 * 36, 256, 0, stream>>>(
                hb, wb_sa_qkv + (size_t)i * E_QKV, sa_qkv_b + (size_t)i * 4608,
                qkv, nullptr, NTOK, 4608, D_MODEL);
            attn_kernel<true, true><<<BB * NH, 256, 0, stream>>>(
                qkv, 4608, 0, qkv, 4608, 1536, qkv, 4608, 3072, attno);
            gemm_bf16_kernel<0><<<16 * 12, 256, 0, stream>>>(
                attno, wb_sa_out + (size_t)i * E_SQ, sa_out_b + (size_t)i * D_MODEL,
                proj, nullptr, NTOK, D_MODEL, D_MODEL);
            ln_kernel<true><<<NTOK, 256, 0, stream>>>(h, proj, ln1_w + i * D_MODEL, ln1_b + i * D_MODEL, h, hb);

            gemm_bf16_kernel<0><<<16 * 12, 256, 0, stream>>>(
                hb, wb_ca_qkv + (size_t)i * E_QKV, ca_qkv_b + (size_t)i * 4608,
                cq, nullptr, NTOK, D_MODEL, D_MODEL);
            gemm_bf16_kernel<0><<<16 * 24, 256, 0, stream>>>(
                memb, wb_ca_qkv + (size_t)i * E_QKV + (size_t)1536 * D_MODEL,
                ca_qkv_b + (size_t)i * 4608 + 1536,
                ckv, nullptr, NTOK, 3072, D_MODEL);
            attn_kernel<false, true><<<BB * NH, 256, 0, stream>>>(
                cq, 1536, 0, ckv, 3072, 0, ckv, 3072, 1536, attno);
            gemm_bf16_kernel<0><<<16 * 12, 256, 0, stream>>>(
                attno, wb_ca_out + (size_t)i * E_SQ, ca_out_b + (size_t)i * D_MODEL,
                proj, nullptr, NTOK, D_MODEL, D_MODEL);
            ln_kernel<true><<<NTOK, 256, 0, stream>>>(h, proj, ln2_w + i * D_MODEL, ln2_b + i * D_MODEL, h, hb);

            gemm_bf16_kernel<1><<<16 * 16, 256, 0, stream>>>(
                hb, wb_ff1 + (size_t)i * E_F1, ff1_b + (size_t)i * 2048,
                nullptr, ffmid, NTOK, 2048, D_MODEL);
            gemm_bf16_kernel<0><<<16 * 12, 256, 0, stream>>>(
                ffmid, wb_ff2 + (size_t)i * E_F1, ff2_b + (size_t)i * D_MODEL,
                proj, nullptr, NTOK, D_MODEL, 2048);
            ln_kernel<true><<<NTOK, 256, 0, stream>>>(h, proj, ln3_w + i * D_MODEL, ln3_b + i * D_MODEL, h, hb);
        }

        slice_kernel<<<(BB * 63 * (D_MODEL / 4) + 255) / 256, 256, 0, stream>>>(h, outp);
        return;
    }

    // ---------- fallback: fp32 path ----------
    float* wsf   = (float*)d_ws;
    float* memF  = wsf;
    float* hF    = memF  + (size_t)NTOK * D_MODEL;
    float* qkvF  = hF    + (size_t)NTOK * D_MODEL;
    float* attnoF= qkvF  + (size_t)NTOK * 4608;
    float* projF = attnoF+ (size_t)NTOK * D_MODEL;
    float* ffmidF= projF + (size_t)NTOK * D_MODEL;
    float* ckvF  = ffmidF+ (size_t)NTOK * 2048;
    float* cqF   = ckvF  + (size_t)NTOK * 3072;

    fusedpool_kernel<<<NTOK, 256, 0, stream>>>(x, pooler_w, pooler_b, pos,
                                               hF, nullptr, nullptr, memF);

    for (int i = 0; i < 2; ++i) {
        gemm_kernel<<<dim3(36, 8), 256, 0, stream>>>(
            hF, sa_qkv_w + (size_t)i * 4608 * D_MODEL, sa_qkv_b + (size_t)i * 4608,
            qkvF, NTOK, 4608, D_MODEL, 0);
        attn_kernel<true, false><<<BB * NH, 256, 0, stream>>>(
            qkvF, 4608, 0, qkvF, 4608, 1536, qkvF, 4608, 3072, attnoF);
        gemm_kernel<<<dim3(12, 8), 256, 0, stream>>>(
            attnoF, sa_out_w + (size_t)i * D_MODEL * D_MODEL, sa_out_b + (size_t)i * D_MODEL,
            projF, NTOK, D_MODEL, D_MODEL, 0);
        ln_kernel<false><<<NTOK, 256, 0, stream>>>(hF, projF, ln1_w + i * D_MODEL, ln1_b + i * D_MODEL, hF, nullptr);

        gemm_kernel<<<dim3(12, 8), 256, 0, stream>>>(
            hF, ca_qkv_w + (size_t)i * 4608 * D_MODEL, ca_qkv_b + (size_t)i * 4608,
            cqF, NTOK, D_MODEL, D_MODEL, 0);
        gemm_kernel<<<dim3(24, 8), 256, 0, stream>>>(
            memF, ca_qkv_w + (size_t)i * 4608 * D_MODEL + (size_t)1536 * D_MODEL,
            ca_qkv_b + (size_t)i * 4608 + 1536,
            ckvF, NTOK, 3072, D_MODEL, 0);
        attn_kernel<false, false><<<BB * NH, 256, 0, stream>>>(
            cqF, 1536, 0, ckvF, 3072, 0, ckvF, 3072, 1536, attnoF);
        gemm_kernel<<<dim3(12, 8), 256, 0, stream>>>(
            attnoF, ca_out_w + (size_t)i * D_MODEL * D_MODEL, ca_out_b + (size_t)i * D_MODEL,
            projF, NTOK, D_MODEL, D_MODEL, 0);
        ln_kernel<false><<<NTOK, 256, 0, stream>>>(hF, projF, ln2_w + i * D_MODEL, ln2_b + i * D_MODEL, hF, nullptr);

        gemm_kernel<<<dim3(16, 8), 256, 0, stream>>>(
            hF, ff1_w + (size_t)i * 2048 * D_MODEL, ff1_b + (size_t)i * 2048,
            ffmidF, NTOK, 2048, D_MODEL, 1);
        gemm_kernel<<<dim3(12, 8), 256, 0, stream>>>(
            ffmidF, ff2_w + (size_t)i * D_MODEL * 2048, ff2_b + (size_t)i * D_MODEL,
            projF, NTOK, D_MODEL, 2048, 0);
        ln_kernel<false><<<NTOK, 256, 0, stream>>>(hF, projF, ln3_w + i * D_MODEL, ln3_b + i * D_MODEL, hF, nullptr);
    }

    slice_kernel<<<(BB * 63 * (D_MODEL / 4) + 255) / 256, 256, 0, stream>>>(hF, outp);
}

// Round 6
// 826.686 us; speedup vs baseline: 2.0947x; 1.2871x over previous
//
#include <hip/hip_runtime.h>
#include <math.h>

#define D_MODEL 1536
#define NH      8
#define HD      192
#define BB      16
#define LL      64
#define UU      64
#define NTOK    1024
#define EPSF    1e-5f

typedef __bf16 bf16;
typedef __bf16 bf16x4_t __attribute__((ext_vector_type(4)));
typedef __bf16 bf16x8_t __attribute__((ext_vector_type(8)));
typedef float  f32x4_t  __attribute__((ext_vector_type(4)));

__device__ __forceinline__ void gload_lds16(const bf16* g, bf16* l) {
    __builtin_amdgcn_global_load_lds((const __attribute__((address_space(1))) void*)g,
                                     (__attribute__((address_space(3))) void*)l, 16, 0, 0);
}

// ---------------- weight fp32 -> bf16 convert ----------------
__global__ __launch_bounds__(256)
void cvt_kernel(const float* __restrict__ s, bf16* __restrict__ d, int n4)
{
    int i = blockIdx.x * 256 + threadIdx.x;
    const int stride = gridDim.x * 256;
    for (; i < n4; i += stride) {
        const float4 v = ((const float4*)s)[i];
        bf16x4_t o = { (bf16)v.x, (bf16)v.y, (bf16)v.z, (bf16)v.w };
        ((bf16x4_t*)d)[i] = o;
    }
}

// ---------------- fused pooling: softmax(x@pw) @ x + pos, one x pass ------
__global__ __launch_bounds__(256)
void fusedpool_kernel(const float* __restrict__ x, const float* __restrict__ pw,
                      const float* __restrict__ pb, const float* __restrict__ pos,
                      float* __restrict__ h, bf16* __restrict__ hb,
                      bf16* __restrict__ memb)
{
    __shared__ float red[2][4];
    const int t = threadIdx.x, wave = t >> 6, lane = t & 63;
    const int bl = blockIdx.x, l = bl & (LL - 1);
    const float* xb = x + (size_t)bl * UU * D_MODEL;

    float pwr[6];
#pragma unroll
    for (int j = 0; j < 6; ++j) pwr[j] = pw[t + j * 256];
    const float pb0 = pb[0];

    float xv[2][6];
#pragma unroll
    for (int j = 0; j < 6; ++j) xv[0][j] = xb[t + j * 256];

    float m = -__builtin_inff(), den = 0.f;
    float acc[6] = {0.f, 0.f, 0.f, 0.f, 0.f, 0.f};

    for (int u = 0; u < UU; ++u) {
        const int cur = u & 1;
        if (u < UU - 1) {
            const float* xn = xb + (size_t)(u + 1) * D_MODEL;
#pragma unroll
            for (int j = 0; j < 6; ++j) xv[cur ^ 1][j] = xn[t + j * 256];
        }
        float p = 0.f;
#pragma unroll
        for (int j = 0; j < 6; ++j) p += xv[cur][j] * pwr[j];
#pragma unroll
        for (int off = 32; off; off >>= 1) p += __shfl_xor(p, off, 64);
        if (lane == 0) red[cur][wave] = p;
        __syncthreads();
        const float logit = red[cur][0] + red[cur][1] + red[cur][2] + red[cur][3] + pb0;
        const float nm = fmaxf(m, logit);
        const float sc = __expf(m - nm);
        const float w  = __expf(logit - nm);
#pragma unroll
        for (int j = 0; j < 6; ++j) acc[j] = acc[j] * sc + w * xv[cur][j];
        den = den * sc + w;
        m = nm;
    }

    const float inv = 1.f / den;
    const size_t db = (size_t)bl * D_MODEL;
    const int pp = l * D_MODEL;
#pragma unroll
    for (int j = 0; j < 6; ++j) {
        const int d = t + j * 256;
        const float v = acc[j] * inv + pos[pp + d];
        h[db + d] = v;
        hb[db + d] = (bf16)v;
        memb[db + d] = (bf16)v;
    }
}

// ---------------- bf16 GEMM, 2-phase double-buffered K-loop ---------------
// C = A(M=1024,K) @ W(N,K)^T + bias.  BM=64, BN=128, BK=64.
// MODE 0: fp32 out C; 1: relu+bf16 out Cb.
#define GBM 64
#define GBN 128

template<int MODE>
__global__ __launch_bounds__(256, 3)
void gemm_bf16_kernel(const bf16* __restrict__ A, const bf16* __restrict__ W,
                      const float* __restrict__ bias, float* __restrict__ C,
                      bf16* __restrict__ Cb, int N, int K)
{
    __shared__ bf16 As[2][GBM * 64];
    __shared__ bf16 Bs[2][GBN * 64];
    const int t = threadIdx.x, wave = t >> 6, lane = t & 63;

    // XCD-chunked bijective swizzle (grid always multiple of 8)
    const int T = gridDim.x;
    const int fid = blockIdx.x;
    const int vid = (fid & 7) * (T >> 3) + (fid >> 3);
    const int m0 = (vid & 15) * GBM;       // M/GBM == 16 always (M=1024)
    const int n0 = (vid >> 4) * GBN;

    const int wr = wave >> 1, wc = wave & 1;
    const int frow = lane & 15, kq = lane >> 4, s = frow & 7;
    const int lr = lane >> 3;
    const int g8 = ((lane & 7) ^ lr) * 8;   // pre-swizzled source granule (elems)

    f32x4_t acc[2][4] = {};

    const bf16* Abase = A + (size_t)(m0 + wave * 8 + lr) * K + g8;
    const bf16* Wbase = W + (size_t)(n0 + wave * 8 + lr) * K + g8;

    // prologue: stage tile 0 into buf 0
#pragma unroll
    for (int i = 0; i < 2; ++i)
        gload_lds16(Abase + (size_t)(i * 32) * K, &As[0][wave * 512] + i * 2048);
#pragma unroll
    for (int i = 0; i < 4; ++i)
        gload_lds16(Wbase + (size_t)(i * 32) * K, &Bs[0][wave * 512] + i * 2048);
    __syncthreads();

    const int nt = K >> 6;
    int cur = 0;
    for (int tt = 0; tt < nt; ++tt) {
        if (tt + 1 < nt) {                  // issue next tile under compute
            const int k0 = (tt + 1) << 6;
#pragma unroll
            for (int i = 0; i < 2; ++i)
                gload_lds16(Abase + k0 + (size_t)(i * 32) * K, &As[cur ^ 1][wave * 512] + i * 2048);
#pragma unroll
            for (int i = 0; i < 4; ++i)
                gload_lds16(Wbase + k0 + (size_t)(i * 32) * K, &Bs[cur ^ 1][wave * 512] + i * 2048);
        }
#pragma unroll
        for (int kk = 0; kk < 2; ++kk) {
            const int gg = (((kk << 2) | kq) ^ s) * 8;
            bf16x8_t af[2], bv[4];
#pragma unroll
            for (int mi = 0; mi < 2; ++mi)
                af[mi] = *(const bf16x8_t*)&As[cur][(wr * 32 + mi * 16 + frow) * 64 + gg];
#pragma unroll
            for (int ni = 0; ni < 4; ++ni)
                bv[ni] = *(const bf16x8_t*)&Bs[cur][(wc * 64 + ni * 16 + frow) * 64 + gg];
#pragma unroll
            for (int mi = 0; mi < 2; ++mi)
#pragma unroll
                for (int ni = 0; ni < 4; ++ni)
                    acc[mi][ni] = __builtin_amdgcn_mfma_f32_16x16x32_bf16(af[mi], bv[ni], acc[mi][ni], 0, 0, 0);
        }
        __syncthreads();   // drains vmcnt (next tile landed) + protects reuse
        cur ^= 1;
    }

    const int crow = m0 + wr * 32 + kq * 4;
    const int ccol = n0 + wc * 64 + frow;
#pragma unroll
    for (int mi = 0; mi < 2; ++mi)
#pragma unroll
        for (int ni = 0; ni < 4; ++ni) {
            const int col = ccol + ni * 16;
            const float bvv = bias[col];
            const int rb = crow + mi * 16;
#pragma unroll
            for (int j = 0; j < 4; ++j) {
                float v = acc[mi][ni][j] + bvv;
                if (MODE == 0) {
                    C[(size_t)(rb + j) * N + col] = v;
                } else {
                    Cb[(size_t)(rb + j) * N + col] = (bf16)fmaxf(v, 0.f);
                }
            }
        }
}

// ---------------- fp32 attention, 4 q-chunks per (b,h) --------------------
// Verified round-3 inner math; grid = BB*NH*4 = 512 blocks for occupancy.
template<bool CAUSAL>
__global__ __launch_bounds__(256)
void attn_kernel(const float* __restrict__ qbuf, int qstride, int qoff0,
                 const float* __restrict__ kbuf, int kstride, int koff0,
                 const float* __restrict__ vbuf, int vstride, int voff0,
                 bf16* __restrict__ out)
{
    __shared__ float kv[HD * 64];    // K phase: K^T swizzled [d][k]; V phase: [k][d]
    __shared__ float sc[16 * 64];    // this chunk's P rows
    const int t = threadIdx.x, wave = t >> 6, lane = t & 63;
    const int bh = blockIdx.x >> 2, qh = blockIdx.x & 3;
    const int b = bh >> 3, hh = bh & 7;
    const int t0 = b * 64;
    const float scale = rsqrtf((float)HD);

    // stage K transposed + XOR swizzle: K[r][c] -> kv[c*64 + (r ^ (c&31))]
    for (int i = 0; i < 48; ++i) {
        const int idx = t + i * 256;
        const int r = idx / HD, c = idx % HD;
        kv[c * 64 + (r ^ (c & 31))] = kbuf[(size_t)(t0 + r) * kstride + koff0 + hh * HD + c];
    }
    __syncthreads();

    // scores for q rows [qh*16, qh*16+16); wave handles 4 rows; lane = k
    for (int qi = 0; qi < 4; ++qi) {
        const int ql = wave * 4 + qi;
        const int q = qh * 16 + ql;
        const float* qr = qbuf + (size_t)(t0 + q) * qstride + qoff0 + hh * HD;
        float a = 0.f;
#pragma unroll 8
        for (int d = 0; d < HD; ++d)
            a += qr[d] * kv[d * 64 + (lane ^ (d & 31))];
        a *= scale;
        if (CAUSAL && lane > q) a = -__builtin_inff();
        float m = a;
#pragma unroll
        for (int off = 32; off; off >>= 1) m = fmaxf(m, __shfl_xor(m, off, 64));
        float e = (CAUSAL && lane > q) ? 0.f : __expf(a - m);
        float s = e;
#pragma unroll
        for (int off = 32; off; off >>= 1) s += __shfl_xor(s, off, 64);
        sc[ql * 64 + lane] = e / s;
    }
    __syncthreads();

    // stage V linear [k][d]
    for (int i = 0; i < 48; ++i) {
        const int idx = t + i * 256;
        const int r = idx / HD, c = idx % HD;
        kv[r * HD + c] = vbuf[(size_t)(t0 + r) * vstride + voff0 + hh * HD + c];
    }
    __syncthreads();

    // PV: lane covers d = lane + 64*dj
    for (int qi = 0; qi < 4; ++qi) {
        const int ql = wave * 4 + qi;
        const int q = qh * 16 + ql;
        float o0 = 0.f, o1 = 0.f, o2 = 0.f;
#pragma unroll 8
        for (int k = 0; k < 64; ++k) {
            const float p = sc[ql * 64 + k];
            o0 += p * kv[k * HD + lane];
            o1 += p * kv[k * HD + 64 + lane];
            o2 += p * kv[k * HD + 128 + lane];
        }
        bf16* op = out + (size_t)(t0 + q) * D_MODEL + hh * HD;
        op[lane] = (bf16)o0; op[64 + lane] = (bf16)o1; op[128 + lane] = (bf16)o2;
    }
}

// ---------------- residual + LayerNorm (fp32 in, fp32 + bf16 out) ---------
__global__ __launch_bounds__(256)
void ln_kernel(const float* __restrict__ a, const float* __restrict__ r,
               const float* __restrict__ w, const float* __restrict__ bb,
               float* __restrict__ out, bf16* __restrict__ outb)
{
    __shared__ float red[8];
    const int tok = blockIdx.x, t = threadIdx.x;
    const int wave = t >> 6, lane = t & 63;
    const float* ap = a + (size_t)tok * D_MODEL;
    const float* rp = r + (size_t)tok * D_MODEL;
    float v[6];
    float s = 0.f;
#pragma unroll
    for (int j = 0; j < 6; ++j) { v[j] = ap[t + j * 256] + rp[t + j * 256]; s += v[j]; }
#pragma unroll
    for (int off = 32; off; off >>= 1) s += __shfl_xor(s, off, 64);
    if (lane == 0) red[wave] = s;
    __syncthreads();
    const float mu = (red[0] + red[1] + red[2] + red[3]) * (1.f / D_MODEL);
    float s2 = 0.f;
#pragma unroll
    for (int j = 0; j < 6; ++j) { const float d = v[j] - mu; s2 += d * d; }
#pragma unroll
    for (int off = 32; off; off >>= 1) s2 += __shfl_xor(s2, off, 64);
    if (lane == 0) red[4 + wave] = s2;
    __syncthreads();
    const float var = (red[4] + red[5] + red[6] + red[7]) * (1.f / D_MODEL);
    const float inv = rsqrtf(var + EPSF);
#pragma unroll
    for (int j = 0; j < 6; ++j) {
        const int d = t + j * 256;
        const float o = (v[j] - mu) * inv * w[d] + bb[d];
        out[(size_t)tok * D_MODEL + d] = o;
        outb[(size_t)tok * D_MODEL + d] = (bf16)o;
    }
}

// ---------------- output slice h[:, :63, :] ----------------
__global__ __launch_bounds__(256)
void slice_kernel(const float* __restrict__ h, float* __restrict__ out)
{
    const int i = blockIdx.x * 256 + threadIdx.x;
    if (i >= BB * 63 * (D_MODEL / 4)) return;
    const int d4 = i % (D_MODEL / 4);
    const int tl = i / (D_MODEL / 4);
    const int b = tl / 63, l = tl % 63;
    ((float4*)out)[i] = ((const float4*)(h + (size_t)(b * 64 + l) * D_MODEL))[d4];
}

extern "C" void kernel_launch(void* const* d_in, const int* in_sizes, int n_in,
                              void* d_out, int out_size, void* d_ws, size_t ws_size,
                              hipStream_t stream)
{
    (void)in_sizes; (void)n_in; (void)out_size; (void)ws_size;
    const float* x        = (const float*)d_in[0];
    const float* pooler_w = (const float*)d_in[1];
    const float* pooler_b = (const float*)d_in[2];
    const float* pos      = (const float*)d_in[3];
    const float* sa_qkv_w = (const float*)d_in[4];
    const float* sa_qkv_b = (const float*)d_in[5];
    const float* sa_out_w = (const float*)d_in[6];
    const float* sa_out_b = (const float*)d_in[7];
    const float* ca_qkv_w = (const float*)d_in[8];
    const float* ca_qkv_b = (const float*)d_in[9];
    const float* ca_out_w = (const float*)d_in[10];
    const float* ca_out_b = (const float*)d_in[11];
    const float* ff1_w    = (const float*)d_in[12];
    const float* ff1_b    = (const float*)d_in[13];
    const float* ff2_w    = (const float*)d_in[14];
    const float* ff2_b    = (const float*)d_in[15];
    const float* ln1_w    = (const float*)d_in[16];
    const float* ln1_b    = (const float*)d_in[17];
    const float* ln2_w    = (const float*)d_in[18];
    const float* ln2_b    = (const float*)d_in[19];
    const float* ln3_w    = (const float*)d_in[20];
    const float* ln3_b    = (const float*)d_in[21];
    float* outp = (float*)d_out;

    char* ws = (char*)d_ws;
    size_t off = 0;
    auto alloc = [&](size_t bytes) { char* p = ws + off; off += (bytes + 255) & ~(size_t)255; return p; };

    const size_t E_QKV = (size_t)4608 * D_MODEL;
    const size_t E_SQ  = (size_t)D_MODEL * D_MODEL;
    const size_t E_F1  = (size_t)2048 * D_MODEL;

    bf16* wb_sa_qkv = (bf16*)alloc(2 * E_QKV * 2);
    bf16* wb_sa_out = (bf16*)alloc(2 * E_SQ * 2);
    bf16* wb_ca_qkv = (bf16*)alloc(2 * E_QKV * 2);
    bf16* wb_ca_out = (bf16*)alloc(2 * E_SQ * 2);
    bf16* wb_ff1    = (bf16*)alloc(2 * E_F1 * 2);
    bf16* wb_ff2    = (bf16*)alloc(2 * E_F1 * 2);
    float* h     = (float*)alloc((size_t)NTOK * D_MODEL * 4);
    bf16*  hb    = (bf16*) alloc((size_t)NTOK * D_MODEL * 2);
    bf16*  memb  = (bf16*) alloc((size_t)NTOK * D_MODEL * 2);
    float* qkv   = (float*)alloc((size_t)NTOK * 4608 * 4);
    bf16*  attno = (bf16*) alloc((size_t)NTOK * D_MODEL * 2);
    float* proj  = (float*)alloc((size_t)NTOK * D_MODEL * 4);
    bf16*  ffmid = (bf16*) alloc((size_t)NTOK * 2048 * 2);

    float* cq  = qkv;                          // aliases, free outside self-attn
    float* ckv = qkv + (size_t)NTOK * D_MODEL;

    cvt_kernel<<<1024, 256, 0, stream>>>(sa_qkv_w, wb_sa_qkv, (int)(2 * E_QKV / 4));
    cvt_kernel<<<512,  256, 0, stream>>>(sa_out_w, wb_sa_out, (int)(2 * E_SQ  / 4));
    cvt_kernel<<<1024, 256, 0, stream>>>(ca_qkv_w, wb_ca_qkv, (int)(2 * E_QKV / 4));
    cvt_kernel<<<512,  256, 0, stream>>>(ca_out_w, wb_ca_out, (int)(2 * E_SQ  / 4));
    cvt_kernel<<<512,  256, 0, stream>>>(ff1_w,    wb_ff1,    (int)(2 * E_F1  / 4));
    cvt_kernel<<<512,  256, 0, stream>>>(ff2_w,    wb_ff2,    (int)(2 * E_F1  / 4));

    fusedpool_kernel<<<NTOK, 256, 0, stream>>>(x, pooler_w, pooler_b, pos, h, hb, memb);

    for (int i = 0; i < 2; ++i) {
        gemm_bf16_kernel<0><<<16 * 36, 256, 0, stream>>>(
            hb, wb_sa_qkv + (size_t)i * E_QKV, sa_qkv_b + (size_t)i * 4608,
            qkv, nullptr, 4608, D_MODEL);
        attn_kernel<true><<<BB * NH * 4, 256, 0, stream>>>(
            qkv, 4608, 0, qkv, 4608, 1536, qkv, 4608, 3072, attno);
        gemm_bf16_kernel<0><<<16 * 12, 256, 0, stream>>>(
            attno, wb_sa_out + (size_t)i * E_SQ, sa_out_b + (size_t)i * D_MODEL,
            proj, nullptr, D_MODEL, D_MODEL);
        ln_kernel<<<NTOK, 256, 0, stream>>>(h, proj, ln1_w + i * D_MODEL, ln1_b + i * D_MODEL, h, hb);

        gemm_bf16_kernel<0><<<16 * 12, 256, 0, stream>>>(
            hb, wb_ca_qkv + (size_t)i * E_QKV, ca_qkv_b + (size_t)i * 4608,
            cq, nullptr, D_MODEL, D_MODEL);
        gemm_bf16_kernel<0><<<16 * 24, 256, 0, stream>>>(
            memb, wb_ca_qkv + (size_t)i * E_QKV + (size_t)1536 * D_MODEL,
            ca_qkv_b + (size_t)i * 4608 + 1536,
            ckv, nullptr, 3072, D_MODEL);
        attn_kernel<false><<<BB * NH * 4, 256, 0, stream>>>(
            cq, 1536, 0, ckv, 3072, 0, ckv, 3072, 1536, attno);
        gemm_bf16_kernel<0><<<16 * 12, 256, 0, stream>>>(
            attno, wb_ca_out + (size_t)i * E_SQ, ca_out_b + (size_t)i * D_MODEL,
            proj, nullptr, D_MODEL, D_MODEL);
        ln_kernel<<<NTOK, 256, 0, stream>>>(h, proj, ln2_w + i * D_MODEL, ln2_b + i * D_MODEL, h, hb);

        gemm_bf16_kernel<1><<<16 * 16, 256, 0, stream>>>(
            hb, wb_ff1 + (size_t)i * E_F1, ff1_b + (size_t)i * 2048,
            nullptr, ffmid, 2048, D_MODEL);
        gemm_bf16_kernel<0><<<16 * 12, 256, 0, stream>>>(
            ffmid, wb_ff2 + (size_t)i * E_F1, ff2_b + (size_t)i * D_MODEL,
            proj, nullptr, D_MODEL, 2048);
        ln_kernel<<<NTOK, 256, 0, stream>>>(h, proj, ln3_w + i * D_MODEL, ln3_b + i * D_MODEL, h, hb);
    }

    slice_kernel<<<(BB * 63 * (D_MODEL / 4) + 255) / 256, 256, 0, stream>>>(h, outp);
}

// Round 7
// 773.825 us; speedup vs baseline: 2.2378x; 1.0683x over previous
//
#include <hip/hip_runtime.h>
#include <math.h>

#define D_MODEL 1536
#define NH      8
#define HD      192
#define BB      16
#define LL      64
#define UU      64
#define NTOK    1024
#define EPSF    1e-5f

typedef __bf16 bf16;
typedef __bf16 bf16x4_t __attribute__((ext_vector_type(4)));
typedef __bf16 bf16x8_t __attribute__((ext_vector_type(8)));
typedef float  f32x4_t  __attribute__((ext_vector_type(4)));

__device__ __forceinline__ void gload_lds16(const bf16* g, bf16* l) {
    __builtin_amdgcn_global_load_lds((const __attribute__((address_space(1))) void*)g,
                                     (__attribute__((address_space(3))) void*)l, 16, 0, 0);
}

// ---------------- all-weights fp32 -> bf16 (dst segments contiguous) ------
__global__ __launch_bounds__(256)
void cvt_all_kernel(const float* __restrict__ s0, const float* __restrict__ s1,
                    const float* __restrict__ s2, const float* __restrict__ s3,
                    const float* __restrict__ s4, const float* __restrict__ s5,
                    bf16* __restrict__ dst)
{
    const int c0 = 3538944, c1 = 4718592, c2 = 8257536,
              c3 = 9437184, c4 = 11010048, c5 = 12582912;   // float4 boundaries
    for (int i = blockIdx.x * 256 + threadIdx.x; i < c5; i += gridDim.x * 256) {
        const float* s; int j;
        if      (i < c0) { s = s0; j = i; }
        else if (i < c1) { s = s1; j = i - c0; }
        else if (i < c2) { s = s2; j = i - c1; }
        else if (i < c3) { s = s3; j = i - c2; }
        else if (i < c4) { s = s4; j = i - c3; }
        else             { s = s5; j = i - c4; }
        const float4 v = ((const float4*)s)[j];
        bf16x4_t o = { (bf16)v.x, (bf16)v.y, (bf16)v.z, (bf16)v.w };
        ((bf16x4_t*)dst)[i] = o;
    }
}

// ---------------- fused pooling: softmax(x@pw) @ x + pos, one x pass ------
__global__ __launch_bounds__(256)
void fusedpool_kernel(const float* __restrict__ x, const float* __restrict__ pw,
                      const float* __restrict__ pb, const float* __restrict__ pos,
                      float* __restrict__ h, bf16* __restrict__ hb,
                      bf16* __restrict__ memb)
{
    __shared__ float red[2][4];
    const int t = threadIdx.x, wave = t >> 6, lane = t & 63;
    const int bl = blockIdx.x, l = bl & (LL - 1);
    const float* xb = x + (size_t)bl * UU * D_MODEL;

    float pwr[6];
#pragma unroll
    for (int j = 0; j < 6; ++j) pwr[j] = pw[t + j * 256];
    const float pb0 = pb[0];

    float xv[2][6];
#pragma unroll
    for (int j = 0; j < 6; ++j) xv[0][j] = xb[t + j * 256];

    float m = -__builtin_inff(), den = 0.f;
    float acc[6] = {0.f, 0.f, 0.f, 0.f, 0.f, 0.f};

    for (int u = 0; u < UU; ++u) {
        const int cur = u & 1;
        if (u < UU - 1) {
            const float* xn = xb + (size_t)(u + 1) * D_MODEL;
#pragma unroll
            for (int j = 0; j < 6; ++j) xv[cur ^ 1][j] = xn[t + j * 256];
        }
        float p = 0.f;
#pragma unroll
        for (int j = 0; j < 6; ++j) p += xv[cur][j] * pwr[j];
#pragma unroll
        for (int off = 32; off; off >>= 1) p += __shfl_xor(p, off, 64);
        if (lane == 0) red[cur][wave] = p;
        __syncthreads();
        const float logit = red[cur][0] + red[cur][1] + red[cur][2] + red[cur][3] + pb0;
        const float nm = fmaxf(m, logit);
        const float sc = __expf(m - nm);
        const float w  = __expf(logit - nm);
#pragma unroll
        for (int j = 0; j < 6; ++j) acc[j] = acc[j] * sc + w * xv[cur][j];
        den = den * sc + w;
        m = nm;
    }

    const float inv = 1.f / den;
    const size_t db = (size_t)bl * D_MODEL;
    const int pp = l * D_MODEL;
#pragma unroll
    for (int j = 0; j < 6; ++j) {
        const int d = t + j * 256;
        const float v = acc[j] * inv + pos[pp + d];
        h[db + d] = v;
        hb[db + d] = (bf16)v;
        memb[db + d] = (bf16)v;
    }
}

// ---------------- bf16 GEMM, 8-wave 512-thread, dbuf 2-phase --------------
// C = A(M=1024,K) @ W(N,K)^T + bias.  BM=64, BN=128, BK=64.
// 8 waves arranged 2m x 4n, each wave computes 32x32 (acc[2][2]).
// MODE 0: fp32 out C; 1: relu+bf16 out.  DUAL: vid>=split runs problem 2.
template<int MODE, bool DUAL>
__global__ __launch_bounds__(512, 4)
void gemm8_kernel(const bf16* __restrict__ A, const bf16* __restrict__ W,
                  const float* __restrict__ bias, void* __restrict__ Cv,
                  int N, int K, int split,
                  const bf16* __restrict__ A2, const bf16* __restrict__ W2,
                  const float* __restrict__ bias2, void* __restrict__ Cv2, int N2)
{
    __shared__ bf16 As[2][64 * 64];
    __shared__ bf16 Bs[2][128 * 64];
    const int t = threadIdx.x, wave = t >> 6, lane = t & 63;

    // XCD-chunked bijective swizzle (all grids multiple of 8)
    const int T = gridDim.x, fid = blockIdx.x;
    int vid = (fid & 7) * (T >> 3) + (fid >> 3);
    const bf16* Ap = A; const bf16* Wp = W; const float* bp = bias;
    void* Cp = Cv; int Nn = N;
    if (DUAL && vid >= split) { vid -= split; Ap = A2; Wp = W2; bp = bias2; Cp = Cv2; Nn = N2; }
    const int m0 = (vid & 15) * 64;        // M/BM == 16 (M=1024)
    const int n0 = (vid >> 4) * 128;

    const int wm = wave >> 2, wn = wave & 3;     // 2m x 4n waves
    const int frow = lane & 15, kq = lane >> 4, s = frow & 7;
    const int lr = lane >> 3;
    const int g8 = ((lane & 7) ^ lr) * 8;        // pre-swizzled source granule

    f32x4_t acc[2][2] = {};

    // each wave stages 8 A-rows (1 inst) and 2x8 B-rows (2 insts)
    const bf16* Abase = Ap + (size_t)(m0 + wave * 8 + lr) * K + g8;
    const bf16* Wbase = Wp + (size_t)(n0 + wave * 8 + lr) * K + g8;

    // prologue: tile 0 -> buf 0
    gload_lds16(Abase, &As[0][wave * 512]);
    gload_lds16(Wbase, &Bs[0][wave * 512]);
    gload_lds16(Wbase + (size_t)64 * K, &Bs[0][4096 + wave * 512]);
    __syncthreads();

    const int nt = K >> 6;
    int cur = 0;
    for (int tt = 0; tt < nt; ++tt) {
        if (tt + 1 < nt) {                  // issue next tile under compute
            const int k0 = (tt + 1) << 6;
            gload_lds16(Abase + k0, &As[cur ^ 1][wave * 512]);
            gload_lds16(Wbase + k0, &Bs[cur ^ 1][wave * 512]);
            gload_lds16(Wbase + k0 + (size_t)64 * K, &Bs[cur ^ 1][4096 + wave * 512]);
        }
#pragma unroll
        for (int kk = 0; kk < 2; ++kk) {
            const int gg = (((kk << 2) | kq) ^ s) * 8;
            bf16x8_t af[2], bv[2];
#pragma unroll
            for (int mi = 0; mi < 2; ++mi)
                af[mi] = *(const bf16x8_t*)&As[cur][(wm * 32 + mi * 16 + frow) * 64 + gg];
#pragma unroll
            for (int ni = 0; ni < 2; ++ni)
                bv[ni] = *(const bf16x8_t*)&Bs[cur][(wn * 32 + ni * 16 + frow) * 64 + gg];
#pragma unroll
            for (int mi = 0; mi < 2; ++mi)
#pragma unroll
                for (int ni = 0; ni < 2; ++ni)
                    acc[mi][ni] = __builtin_amdgcn_mfma_f32_16x16x32_bf16(af[mi], bv[ni], acc[mi][ni], 0, 0, 0);
        }
        __syncthreads();   // drains vmcnt (next tile landed) + protects reuse
        cur ^= 1;
    }

    const int crow = m0 + wm * 32 + kq * 4;
    const int ccol = n0 + wn * 32 + frow;
#pragma unroll
    for (int mi = 0; mi < 2; ++mi)
#pragma unroll
        for (int ni = 0; ni < 2; ++ni) {
            const int col = ccol + ni * 16;
            const float bvv = bp[col];
            const int rb = crow + mi * 16;
#pragma unroll
            for (int j = 0; j < 4; ++j) {
                float v = acc[mi][ni][j] + bvv;
                if (MODE == 0) {
                    ((float*)Cp)[(size_t)(rb + j) * Nn + col] = v;
                } else {
                    ((bf16*)Cp)[(size_t)(rb + j) * Nn + col] = (bf16)fmaxf(v, 0.f);
                }
            }
        }
}

// ---------------- fp32 attention, 4 q-chunks per (b,h) --------------------
template<bool CAUSAL>
__global__ __launch_bounds__(256)
void attn_kernel(const float* __restrict__ qbuf, int qstride, int qoff0,
                 const float* __restrict__ kbuf, int kstride, int koff0,
                 const float* __restrict__ vbuf, int vstride, int voff0,
                 bf16* __restrict__ out)
{
    __shared__ float kv[HD * 64];    // K phase: K^T swizzled [d][k]; V phase: [k][d]
    __shared__ float sc[16 * 64];    // this chunk's P rows
    const int t = threadIdx.x, wave = t >> 6, lane = t & 63;
    const int bh = blockIdx.x >> 2, qh = blockIdx.x & 3;
    const int b = bh >> 3, hh = bh & 7;
    const int t0 = b * 64;
    const float scale = rsqrtf((float)HD);

    for (int i = 0; i < 48; ++i) {
        const int idx = t + i * 256;
        const int r = idx / HD, c = idx % HD;
        kv[c * 64 + (r ^ (c & 31))] = kbuf[(size_t)(t0 + r) * kstride + koff0 + hh * HD + c];
    }
    __syncthreads();

    for (int qi = 0; qi < 4; ++qi) {
        const int ql = wave * 4 + qi;
        const int q = qh * 16 + ql;
        const float* qr = qbuf + (size_t)(t0 + q) * qstride + qoff0 + hh * HD;
        float a = 0.f;
#pragma unroll 8
        for (int d = 0; d < HD; ++d)
            a += qr[d] * kv[d * 64 + (lane ^ (d & 31))];
        a *= scale;
        if (CAUSAL && lane > q) a = -__builtin_inff();
        float m = a;
#pragma unroll
        for (int off = 32; off; off >>= 1) m = fmaxf(m, __shfl_xor(m, off, 64));
        float e = (CAUSAL && lane > q) ? 0.f : __expf(a - m);
        float s = e;
#pragma unroll
        for (int off = 32; off; off >>= 1) s += __shfl_xor(s, off, 64);
        sc[ql * 64 + lane] = e / s;
    }
    __syncthreads();

    for (int i = 0; i < 48; ++i) {
        const int idx = t + i * 256;
        const int r = idx / HD, c = idx % HD;
        kv[r * HD + c] = vbuf[(size_t)(t0 + r) * vstride + voff0 + hh * HD + c];
    }
    __syncthreads();

    for (int qi = 0; qi < 4; ++qi) {
        const int ql = wave * 4 + qi;
        const int q = qh * 16 + ql;
        float o0 = 0.f, o1 = 0.f, o2 = 0.f;
#pragma unroll 8
        for (int k = 0; k < 64; ++k) {
            const float p = sc[ql * 64 + k];
            o0 += p * kv[k * HD + lane];
            o1 += p * kv[k * HD + 64 + lane];
            o2 += p * kv[k * HD + 128 + lane];
        }
        bf16* op = out + (size_t)(t0 + q) * D_MODEL + hh * HD;
        op[lane] = (bf16)o0; op[64 + lane] = (bf16)o1; op[128 + lane] = (bf16)o2;
    }
}

// ---------------- residual + LayerNorm (fp32 in, fp32 + bf16 out) ---------
__global__ __launch_bounds__(256)
void ln_kernel(const float* __restrict__ a, const float* __restrict__ r,
               const float* __restrict__ w, const float* __restrict__ bb,
               float* __restrict__ out, bf16* __restrict__ outb)
{
    __shared__ float red[8];
    const int tok = blockIdx.x, t = threadIdx.x;
    const int wave = t >> 6, lane = t & 63;
    const float* ap = a + (size_t)tok * D_MODEL;
    const float* rp = r + (size_t)tok * D_MODEL;
    float v[6];
    float s = 0.f;
#pragma unroll
    for (int j = 0; j < 6; ++j) { v[j] = ap[t + j * 256] + rp[t + j * 256]; s += v[j]; }
#pragma unroll
    for (int off = 32; off; off >>= 1) s += __shfl_xor(s, off, 64);
    if (lane == 0) red[wave] = s;
    __syncthreads();
    const float mu = (red[0] + red[1] + red[2] + red[3]) * (1.f / D_MODEL);
    float s2 = 0.f;
#pragma unroll
    for (int j = 0; j < 6; ++j) { const float d = v[j] - mu; s2 += d * d; }
#pragma unroll
    for (int off = 32; off; off >>= 1) s2 += __shfl_xor(s2, off, 64);
    if (lane == 0) red[4 + wave] = s2;
    __syncthreads();
    const float var = (red[4] + red[5] + red[6] + red[7]) * (1.f / D_MODEL);
    const float inv = rsqrtf(var + EPSF);
#pragma unroll
    for (int j = 0; j < 6; ++j) {
        const int d = t + j * 256;
        const float o = (v[j] - mu) * inv * w[d] + bb[d];
        out[(size_t)tok * D_MODEL + d] = o;
        outb[(size_t)tok * D_MODEL + d] = (bf16)o;
    }
}

// ---------------- output slice h[:, :63, :] ----------------
__global__ __launch_bounds__(256)
void slice_kernel(const float* __restrict__ h, float* __restrict__ out)
{
    const int i = blockIdx.x * 256 + threadIdx.x;
    if (i >= BB * 63 * (D_MODEL / 4)) return;
    const int d4 = i % (D_MODEL / 4);
    const int tl = i / (D_MODEL / 4);
    const int b = tl / 63, l = tl % 63;
    ((float4*)out)[i] = ((const float4*)(h + (size_t)(b * 64 + l) * D_MODEL))[d4];
}

extern "C" void kernel_launch(void* const* d_in, const int* in_sizes, int n_in,
                              void* d_out, int out_size, void* d_ws, size_t ws_size,
                              hipStream_t stream)
{
    (void)in_sizes; (void)n_in; (void)out_size; (void)ws_size;
    const float* x        = (const float*)d_in[0];
    const float* pooler_w = (const float*)d_in[1];
    const float* pooler_b = (const float*)d_in[2];
    const float* pos      = (const float*)d_in[3];
    const float* sa_qkv_w = (const float*)d_in[4];
    const float* sa_qkv_b = (const float*)d_in[5];
    const float* sa_out_w = (const float*)d_in[6];
    const float* sa_out_b = (const float*)d_in[7];
    const float* ca_qkv_w = (const float*)d_in[8];
    const float* ca_qkv_b = (const float*)d_in[9];
    const float* ca_out_w = (const float*)d_in[10];
    const float* ca_out_b = (const float*)d_in[11];
    const float* ff1_w    = (const float*)d_in[12];
    const float* ff1_b    = (const float*)d_in[13];
    const float* ff2_w    = (const float*)d_in[14];
    const float* ff2_b    = (const float*)d_in[15];
    const float* ln1_w    = (const float*)d_in[16];
    const float* ln1_b    = (const float*)d_in[17];
    const float* ln2_w    = (const float*)d_in[18];
    const float* ln2_b    = (const float*)d_in[19];
    const float* ln3_w    = (const float*)d_in[20];
    const float* ln3_b    = (const float*)d_in[21];
    float* outp = (float*)d_out;

    char* ws = (char*)d_ws;
    size_t off = 0;
    auto alloc = [&](size_t bytes) { char* p = ws + off; off += (bytes + 255) & ~(size_t)255; return p; };

    const size_t E_QKV = (size_t)4608 * D_MODEL;
    const size_t E_SQ  = (size_t)D_MODEL * D_MODEL;
    const size_t E_F1  = (size_t)2048 * D_MODEL;

    // contiguous bf16 weight block (order must match cvt_all boundaries)
    bf16* wb_sa_qkv = (bf16*)alloc(2 * E_QKV * 2);
    bf16* wb_sa_out = (bf16*)alloc(2 * E_SQ * 2);
    bf16* wb_ca_qkv = (bf16*)alloc(2 * E_QKV * 2);
    bf16* wb_ca_out = (bf16*)alloc(2 * E_SQ * 2);
    bf16* wb_ff1    = (bf16*)alloc(2 * E_F1 * 2);
    bf16* wb_ff2    = (bf16*)alloc(2 * E_F1 * 2);
    float* h     = (float*)alloc((size_t)NTOK * D_MODEL * 4);
    bf16*  hb    = (bf16*) alloc((size_t)NTOK * D_MODEL * 2);
    bf16*  memb  = (bf16*) alloc((size_t)NTOK * D_MODEL * 2);
    float* qkv   = (float*)alloc((size_t)NTOK * 4608 * 4);
    float* cq    = (float*)alloc((size_t)NTOK * D_MODEL * 4);
    float* ckv0  = (float*)alloc((size_t)NTOK * 3072 * 4);
    float* ckv1  = (float*)alloc((size_t)NTOK * 3072 * 4);
    bf16*  attno = (bf16*) alloc((size_t)NTOK * D_MODEL * 2);
    float* proj  = (float*)alloc((size_t)NTOK * D_MODEL * 4);
    bf16*  ffmid = (bf16*) alloc((size_t)NTOK * 2048 * 2);

    cvt_all_kernel<<<2048, 256, 0, stream>>>(sa_qkv_w, sa_out_w, ca_qkv_w,
                                             ca_out_w, ff1_w, ff2_w, wb_sa_qkv);
    fusedpool_kernel<<<NTOK, 256, 0, stream>>>(x, pooler_w, pooler_b, pos, h, hb, memb);

    // both layers' cross-attn K/V depend only on memb: one DUAL dispatch up front
    gemm8_kernel<0, true><<<768, 512, 0, stream>>>(
        memb, wb_ca_qkv + (size_t)1536 * D_MODEL, ca_qkv_b + 1536,
        ckv0, 3072, D_MODEL, 384,
        memb, wb_ca_qkv + E_QKV + (size_t)1536 * D_MODEL, ca_qkv_b + 4608 + 1536,
        ckv1, 3072);

    for (int i = 0; i < 2; ++i) {
        float* ckv = i ? ckv1 : ckv0;

        gemm8_kernel<0, false><<<16 * 36, 512, 0, stream>>>(
            hb, wb_sa_qkv + (size_t)i * E_QKV, sa_qkv_b + (size_t)i * 4608,
            qkv, 4608, D_MODEL, 0, nullptr, nullptr, nullptr, nullptr, 0);
        attn_kernel<true><<<BB * NH * 4, 256, 0, stream>>>(
            qkv, 4608, 0, qkv, 4608, 1536, qkv, 4608, 3072, attno);
        gemm8_kernel<0, false><<<16 * 12, 512, 0, stream>>>(
            attno, wb_sa_out + (size_t)i * E_SQ, sa_out_b + (size_t)i * D_MODEL,
            proj, D_MODEL, D_MODEL, 0, nullptr, nullptr, nullptr, nullptr, 0);
        ln_kernel<<<NTOK, 256, 0, stream>>>(h, proj, ln1_w + i * D_MODEL, ln1_b + i * D_MODEL, h, hb);

        gemm8_kernel<0, false><<<16 * 12, 512, 0, stream>>>(
            hb, wb_ca_qkv + (size_t)i * E_QKV, ca_qkv_b + (size_t)i * 4608,
            cq, D_MODEL, D_MODEL, 0, nullptr, nullptr, nullptr, nullptr, 0);
        attn_kernel<false><<<BB * NH * 4, 256, 0, stream>>>(
            cq, 1536, 0, ckv, 3072, 0, ckv, 3072, 1536, attno);
        gemm8_kernel<0, false><<<16 * 12, 512, 0, stream>>>(
            attno, wb_ca_out + (size_t)i * E_SQ, ca_out_b + (size_t)i * D_MODEL,
            proj, D_MODEL, D_MODEL, 0, nullptr, nullptr, nullptr, nullptr, 0);
        ln_kernel<<<NTOK, 256, 0, stream>>>(h, proj, ln2_w + i * D_MODEL, ln2_b + i * D_MODEL, h, hb);

        gemm8_kernel<1, false><<<16 * 16, 512, 0, stream>>>(
            hb, wb_ff1 + (size_t)i * E_F1, ff1_b + (size_t)i * 2048,
            ffmid, 2048, D_MODEL, 0, nullptr, nullptr, nullptr, nullptr, 0);
        gemm8_kernel<0, false><<<16 * 12, 512, 0, stream>>>(
            ffmid, wb_ff2 + (size_t)i * E_F1, ff2_b + (size_t)i * D_MODEL,
            proj, D_MODEL, 2048, 0, nullptr, nullptr, nullptr, nullptr, 0);
        ln_kernel<<<NTOK, 256, 0, stream>>>(h, proj, ln3_w + i * D_MODEL, ln3_b + i * D_MODEL, h, hb);
    }

    slice_kernel<<<(BB * 63 * (D_MODEL / 4) + 255) / 256, 256, 0, stream>>>(h, outp);
}

// Round 8
// 695.285 us; speedup vs baseline: 2.4905x; 1.1130x over previous
//
#include <hip/hip_runtime.h>
#include <math.h>

#define D_MODEL 1536
#define NH      8
#define HD      192
#define BB      16
#define LL      64
#define UU      64
#define NTOK    1024
#define EPSF    1e-5f

typedef __bf16 bf16;
typedef __bf16 bf16x4_t __attribute__((ext_vector_type(4)));
typedef __bf16 bf16x8_t __attribute__((ext_vector_type(8)));
typedef float  f32x4_t  __attribute__((ext_vector_type(4)));

__device__ __forceinline__ void gload_lds16(const bf16* g, bf16* l) {
    __builtin_amdgcn_global_load_lds((const __attribute__((address_space(1))) void*)g,
                                     (__attribute__((address_space(3))) void*)l, 16, 0, 0);
}

// ---------------- all-weights fp32 -> bf16 (dst segments contiguous) ------
__global__ __launch_bounds__(256)
void cvt_all_kernel(const float* __restrict__ s0, const float* __restrict__ s1,
                    const float* __restrict__ s2, const float* __restrict__ s3,
                    const float* __restrict__ s4, const float* __restrict__ s5,
                    bf16* __restrict__ dst)
{
    const int c0 = 3538944, c1 = 4718592, c2 = 8257536,
              c3 = 9437184, c4 = 11010048, c5 = 12582912;   // float4 boundaries
    for (int i = blockIdx.x * 256 + threadIdx.x; i < c5; i += gridDim.x * 256) {
        const float* s; int j;
        if      (i < c0) { s = s0; j = i; }
        else if (i < c1) { s = s1; j = i - c0; }
        else if (i < c2) { s = s2; j = i - c1; }
        else if (i < c3) { s = s3; j = i - c2; }
        else if (i < c4) { s = s4; j = i - c3; }
        else             { s = s5; j = i - c4; }
        const float4 v = ((const float4*)s)[j];
        bf16x4_t o = { (bf16)v.x, (bf16)v.y, (bf16)v.z, (bf16)v.w };
        ((bf16x4_t*)dst)[i] = o;
    }
}

// ---------------- fused pooling: softmax(x@pw) @ x + pos, one x pass ------
__global__ __launch_bounds__(256)
void fusedpool_kernel(const float* __restrict__ x, const float* __restrict__ pw,
                      const float* __restrict__ pb, const float* __restrict__ pos,
                      float* __restrict__ h, bf16* __restrict__ hb,
                      bf16* __restrict__ memb)
{
    __shared__ float red[2][4];
    const int t = threadIdx.x, wave = t >> 6, lane = t & 63;
    const int bl = blockIdx.x, l = bl & (LL - 1);
    const float* xb = x + (size_t)bl * UU * D_MODEL;

    float pwr[6];
#pragma unroll
    for (int j = 0; j < 6; ++j) pwr[j] = pw[t + j * 256];
    const float pb0 = pb[0];

    float xv[2][6];
#pragma unroll
    for (int j = 0; j < 6; ++j) xv[0][j] = xb[t + j * 256];

    float m = -__builtin_inff(), den = 0.f;
    float acc[6] = {0.f, 0.f, 0.f, 0.f, 0.f, 0.f};

    for (int u = 0; u < UU; ++u) {
        const int cur = u & 1;
        if (u < UU - 1) {
            const float* xn = xb + (size_t)(u + 1) * D_MODEL;
#pragma unroll
            for (int j = 0; j < 6; ++j) xv[cur ^ 1][j] = xn[t + j * 256];
        }
        float p = 0.f;
#pragma unroll
        for (int j = 0; j < 6; ++j) p += xv[cur][j] * pwr[j];
#pragma unroll
        for (int off = 32; off; off >>= 1) p += __shfl_xor(p, off, 64);
        if (lane == 0) red[cur][wave] = p;
        __syncthreads();
        const float logit = red[cur][0] + red[cur][1] + red[cur][2] + red[cur][3] + pb0;
        const float nm = fmaxf(m, logit);
        const float sc = __expf(m - nm);
        const float w  = __expf(logit - nm);
#pragma unroll
        for (int j = 0; j < 6; ++j) acc[j] = acc[j] * sc + w * xv[cur][j];
        den = den * sc + w;
        m = nm;
    }

    const float inv = 1.f / den;
    const size_t db = (size_t)bl * D_MODEL;
    const int pp = l * D_MODEL;
#pragma unroll
    for (int j = 0; j < 6; ++j) {
        const int d = t + j * 256;
        const float v = acc[j] * inv + pos[pp + d];
        h[db + d] = v;
        hb[db + d] = (bf16)v;
        memb[db + d] = (bf16)v;
    }
}

// ---------------- bf16 GEMM, 8-wave 512-thread, dbuf 2-phase --------------
// C = A(M=1024,K) @ W(N,K)^T + bias.  BM=64, BN=128, BK=64.
// 8 waves 2m x 4n, each 32x32 (acc[2][2]).
// MODE 0: fp32 out; 1: relu+bf16 out.
// DUAL: vid>=split runs problem 2.  SPLITK: grid doubled, kslice=vid&1,
//   each slice does K/2; partials to Cp + kslice*NTOK*N; bias only slice 0.
template<int MODE, bool DUAL, bool SPLITK>
__global__ __launch_bounds__(512, 4)
void gemm8_kernel(const bf16* __restrict__ A, const bf16* __restrict__ W,
                  const float* __restrict__ bias, void* __restrict__ Cv,
                  int N, int K, int split,
                  const bf16* __restrict__ A2, const bf16* __restrict__ W2,
                  const float* __restrict__ bias2, void* __restrict__ Cv2, int N2)
{
    __shared__ bf16 As[2][64 * 64];
    __shared__ bf16 Bs[2][128 * 64];
    const int t = threadIdx.x, wave = t >> 6, lane = t & 63;

    // XCD-chunked bijective swizzle (all grids multiple of 8)
    const int T = gridDim.x, fid = blockIdx.x;
    int vid = (fid & 7) * (T >> 3) + (fid >> 3);
    const bf16* Ap = A; const bf16* Wp = W; const float* bp = bias;
    void* Cp = Cv; int Nn = N;
    if (DUAL && vid >= split) { vid -= split; Ap = A2; Wp = W2; bp = bias2; Cp = Cv2; Nn = N2; }
    int kslice = 0;
    if (SPLITK) { kslice = vid & 1; vid >>= 1; }
    const int m0 = (vid & 15) * 64;        // M/BM == 16 (M=1024)
    const int n0 = (vid >> 4) * 128;
    const int kbase = SPLITK ? kslice * (K >> 1) : 0;

    const int wm = wave >> 2, wn = wave & 3;     // 2m x 4n waves
    const int frow = lane & 15, kq = lane >> 4, s = frow & 7;
    const int lr = lane >> 3;
    const int g8 = ((lane & 7) ^ lr) * 8;        // pre-swizzled source granule

    f32x4_t acc[2][2] = {};

    const bf16* Abase = Ap + (size_t)(m0 + wave * 8 + lr) * K + kbase + g8;
    const bf16* Wbase = Wp + (size_t)(n0 + wave * 8 + lr) * K + kbase + g8;

    // prologue: tile 0 -> buf 0
    gload_lds16(Abase, &As[0][wave * 512]);
    gload_lds16(Wbase, &Bs[0][wave * 512]);
    gload_lds16(Wbase + (size_t)64 * K, &Bs[0][4096 + wave * 512]);
    __syncthreads();

    const int nt = SPLITK ? (K >> 7) : (K >> 6);
    int cur = 0;
    for (int tt = 0; tt < nt; ++tt) {
        if (tt + 1 < nt) {                  // issue next tile under compute
            const int k0 = (tt + 1) << 6;
            gload_lds16(Abase + k0, &As[cur ^ 1][wave * 512]);
            gload_lds16(Wbase + k0, &Bs[cur ^ 1][wave * 512]);
            gload_lds16(Wbase + k0 + (size_t)64 * K, &Bs[cur ^ 1][4096 + wave * 512]);
        }
#pragma unroll
        for (int kk = 0; kk < 2; ++kk) {
            const int gg = (((kk << 2) | kq) ^ s) * 8;
            bf16x8_t af[2], bv[2];
#pragma unroll
            for (int mi = 0; mi < 2; ++mi)
                af[mi] = *(const bf16x8_t*)&As[cur][(wm * 32 + mi * 16 + frow) * 64 + gg];
#pragma unroll
            for (int ni = 0; ni < 2; ++ni)
                bv[ni] = *(const bf16x8_t*)&Bs[cur][(wn * 32 + ni * 16 + frow) * 64 + gg];
#pragma unroll
            for (int mi = 0; mi < 2; ++mi)
#pragma unroll
                for (int ni = 0; ni < 2; ++ni)
                    acc[mi][ni] = __builtin_amdgcn_mfma_f32_16x16x32_bf16(af[mi], bv[ni], acc[mi][ni], 0, 0, 0);
        }
        __syncthreads();   // drains vmcnt (next tile landed) + protects reuse
        cur ^= 1;
    }

    float* Cpart = (float*)Cp + (SPLITK ? (size_t)kslice * NTOK * Nn : 0);
    const int crow = m0 + wm * 32 + kq * 4;
    const int ccol = n0 + wn * 32 + frow;
#pragma unroll
    for (int mi = 0; mi < 2; ++mi)
#pragma unroll
        for (int ni = 0; ni < 2; ++ni) {
            const int col = ccol + ni * 16;
            const float bvv = (SPLITK && kslice) ? 0.f : bp[col];
            const int rb = crow + mi * 16;
#pragma unroll
            for (int j = 0; j < 4; ++j) {
                float v = acc[mi][ni][j] + bvv;
                if (MODE == 0) {
                    Cpart[(size_t)(rb + j) * Nn + col] = v;
                } else {
                    ((bf16*)Cp)[(size_t)(rb + j) * Nn + col] = (bf16)fmaxf(v, 0.f);
                }
            }
        }
}

// ---------------- split-K reduce + relu -> bf16 (for ff1) -----------------
__global__ __launch_bounds__(256)
void reduce_relu_kernel(const float* __restrict__ p0, const float* __restrict__ p1,
                        bf16* __restrict__ dst, int n4)
{
    const int i = blockIdx.x * 256 + threadIdx.x;
    if (i >= n4) return;
    const float4 a = ((const float4*)p0)[i];
    const float4 b = ((const float4*)p1)[i];
    bf16x4_t o = { (bf16)fmaxf(a.x + b.x, 0.f), (bf16)fmaxf(a.y + b.y, 0.f),
                   (bf16)fmaxf(a.z + b.z, 0.f), (bf16)fmaxf(a.w + b.w, 0.f) };
    ((bf16x4_t*)dst)[i] = o;
}

// ---------------- fp32 attention, 4 q-chunks per (b,h) --------------------
// QSPLIT: q = qbuf + qbuf2 (split-K partials; bias already in partial 0)
template<bool CAUSAL, bool QSPLIT>
__global__ __launch_bounds__(256)
void attn_kernel(const float* __restrict__ qbuf, const float* __restrict__ qbuf2,
                 int qstride, int qoff0,
                 const float* __restrict__ kbuf, int kstride, int koff0,
                 const float* __restrict__ vbuf, int vstride, int voff0,
                 bf16* __restrict__ out)
{
    __shared__ float kv[HD * 64];    // K phase: K^T swizzled [d][k]; V phase: [k][d]
    __shared__ float sc[16 * 64];    // this chunk's P rows
    const int t = threadIdx.x, wave = t >> 6, lane = t & 63;
    const int bh = blockIdx.x >> 2, qh = blockIdx.x & 3;
    const int b = bh >> 3, hh = bh & 7;
    const int t0 = b * 64;
    const float scale = rsqrtf((float)HD);

    for (int i = 0; i < 48; ++i) {
        const int idx = t + i * 256;
        const int r = idx / HD, c = idx % HD;
        kv[c * 64 + (r ^ (c & 31))] = kbuf[(size_t)(t0 + r) * kstride + koff0 + hh * HD + c];
    }
    __syncthreads();

    for (int qi = 0; qi < 4; ++qi) {
        const int ql = wave * 4 + qi;
        const int q = qh * 16 + ql;
        const size_t qb0 = (size_t)(t0 + q) * qstride + qoff0 + hh * HD;
        const float* qr  = qbuf + qb0;
        const float* qr2 = QSPLIT ? (qbuf2 + qb0) : nullptr;
        float a = 0.f;
#pragma unroll 8
        for (int d = 0; d < HD; ++d) {
            const float qv = QSPLIT ? (qr[d] + qr2[d]) : qr[d];
            a += qv * kv[d * 64 + (lane ^ (d & 31))];
        }
        a *= scale;
        if (CAUSAL && lane > q) a = -__builtin_inff();
        float m = a;
#pragma unroll
        for (int off = 32; off; off >>= 1) m = fmaxf(m, __shfl_xor(m, off, 64));
        float e = (CAUSAL && lane > q) ? 0.f : __expf(a - m);
        float s = e;
#pragma unroll
        for (int off = 32; off; off >>= 1) s += __shfl_xor(s, off, 64);
        sc[ql * 64 + lane] = e / s;
    }
    __syncthreads();

    for (int i = 0; i < 48; ++i) {
        const int idx = t + i * 256;
        const int r = idx / HD, c = idx % HD;
        kv[r * HD + c] = vbuf[(size_t)(t0 + r) * vstride + voff0 + hh * HD + c];
    }
    __syncthreads();

    for (int qi = 0; qi < 4; ++qi) {
        const int ql = wave * 4 + qi;
        const int q = qh * 16 + ql;
        float o0 = 0.f, o1 = 0.f, o2 = 0.f;
#pragma unroll 8
        for (int k = 0; k < 64; ++k) {
            const float p = sc[ql * 64 + k];
            o0 += p * kv[k * HD + lane];
            o1 += p * kv[k * HD + 64 + lane];
            o2 += p * kv[k * HD + 128 + lane];
        }
        bf16* op = out + (size_t)(t0 + q) * D_MODEL + hh * HD;
        op[lane] = (bf16)o0; op[64 + lane] = (bf16)o1; op[128 + lane] = (bf16)o2;
    }
}

// ---------------- residual + LayerNorm (3-input, optional slice-out) ------
// out = LN(a + r + r2); r2 is the second split-K partial.
template<bool R2, bool SLICE>
__global__ __launch_bounds__(256)
void ln_kernel(const float* __restrict__ a, const float* __restrict__ r,
               const float* __restrict__ r2,
               const float* __restrict__ w, const float* __restrict__ bb,
               float* __restrict__ out, bf16* __restrict__ outb,
               float* __restrict__ out2)
{
    __shared__ float red[8];
    const int tok = blockIdx.x, t = threadIdx.x;
    const int wave = t >> 6, lane = t & 63;
    const float* ap = a + (size_t)tok * D_MODEL;
    const float* rp = r + (size_t)tok * D_MODEL;
    const float* rp2 = R2 ? (r2 + (size_t)tok * D_MODEL) : nullptr;
    float v[6];
    float s = 0.f;
#pragma unroll
    for (int j = 0; j < 6; ++j) {
        v[j] = ap[t + j * 256] + rp[t + j * 256];
        if (R2) v[j] += rp2[t + j * 256];
        s += v[j];
    }
#pragma unroll
    for (int off = 32; off; off >>= 1) s += __shfl_xor(s, off, 64);
    if (lane == 0) red[wave] = s;
    __syncthreads();
    const float mu = (red[0] + red[1] + red[2] + red[3]) * (1.f / D_MODEL);
    float s2 = 0.f;
#pragma unroll
    for (int j = 0; j < 6; ++j) { const float d = v[j] - mu; s2 += d * d; }
#pragma unroll
    for (int off = 32; off; off >>= 1) s2 += __shfl_xor(s2, off, 64);
    if (lane == 0) red[4 + wave] = s2;
    __syncthreads();
    const float var = (red[4] + red[5] + red[6] + red[7]) * (1.f / D_MODEL);
    const float inv = rsqrtf(var + EPSF);
    const int bq = tok >> 6, lq = tok & 63;
#pragma unroll
    for (int j = 0; j < 6; ++j) {
        const int d = t + j * 256;
        const float o = (v[j] - mu) * inv * w[d] + bb[d];
        out[(size_t)tok * D_MODEL + d] = o;
        outb[(size_t)tok * D_MODEL + d] = (bf16)o;
        if (SLICE && lq < 63) out2[(size_t)(bq * 63 + lq) * D_MODEL + d] = o;
    }
}

extern "C" void kernel_launch(void* const* d_in, const int* in_sizes, int n_in,
                              void* d_out, int out_size, void* d_ws, size_t ws_size,
                              hipStream_t stream)
{
    (void)in_sizes; (void)n_in; (void)out_size; (void)ws_size;
    const float* x        = (const float*)d_in[0];
    const float* pooler_w = (const float*)d_in[1];
    const float* pooler_b = (const float*)d_in[2];
    const float* pos      = (const float*)d_in[3];
    const float* sa_qkv_w = (const float*)d_in[4];
    const float* sa_qkv_b = (const float*)d_in[5];
    const float* sa_out_w = (const float*)d_in[6];
    const float* sa_out_b = (const float*)d_in[7];
    const float* ca_qkv_w = (const float*)d_in[8];
    const float* ca_qkv_b = (const float*)d_in[9];
    const float* ca_out_w = (const float*)d_in[10];
    const float* ca_out_b = (const float*)d_in[11];
    const float* ff1_w    = (const float*)d_in[12];
    const float* ff1_b    = (const float*)d_in[13];
    const float* ff2_w    = (const float*)d_in[14];
    const float* ff2_b    = (const float*)d_in[15];
    const float* ln1_w    = (const float*)d_in[16];
    const float* ln1_b    = (const float*)d_in[17];
    const float* ln2_w    = (const float*)d_in[18];
    const float* ln2_b    = (const float*)d_in[19];
    const float* ln3_w    = (const float*)d_in[20];
    const float* ln3_b    = (const float*)d_in[21];
    float* outp = (float*)d_out;

    char* ws = (char*)d_ws;
    size_t off = 0;
    auto alloc = [&](size_t bytes) { char* p = ws + off; off += (bytes + 255) & ~(size_t)255; return p; };

    const size_t E_QKV = (size_t)4608 * D_MODEL;
    const size_t E_SQ  = (size_t)D_MODEL * D_MODEL;
    const size_t E_F1  = (size_t)2048 * D_MODEL;

    // contiguous bf16 weight block (order must match cvt_all boundaries)
    bf16* wb_sa_qkv = (bf16*)alloc(2 * E_QKV * 2);
    bf16* wb_sa_out = (bf16*)alloc(2 * E_SQ * 2);
    bf16* wb_ca_qkv = (bf16*)alloc(2 * E_QKV * 2);
    bf16* wb_ca_out = (bf16*)alloc(2 * E_SQ * 2);
    bf16* wb_ff1    = (bf16*)alloc(2 * E_F1 * 2);
    bf16* wb_ff2    = (bf16*)alloc(2 * E_F1 * 2);
    float* h     = (float*)alloc((size_t)NTOK * D_MODEL * 4);
    bf16*  hb    = (bf16*) alloc((size_t)NTOK * D_MODEL * 2);
    bf16*  memb  = (bf16*) alloc((size_t)NTOK * D_MODEL * 2);
    float* qkv   = (float*)alloc((size_t)NTOK * 4608 * 4);
    float* cq01  = (float*)alloc((size_t)NTOK * D_MODEL * 4 * 2);   // split-K pair
    float* ckv0  = (float*)alloc((size_t)NTOK * 3072 * 4);
    float* ckv1  = (float*)alloc((size_t)NTOK * 3072 * 4);
    bf16*  attno = (bf16*) alloc((size_t)NTOK * D_MODEL * 2);
    float* proj01= (float*)alloc((size_t)NTOK * D_MODEL * 4 * 2);   // split-K pair
    float* f1p01 = (float*)alloc((size_t)NTOK * 2048 * 4 * 2);      // split-K pair
    bf16*  ffmid = (bf16*) alloc((size_t)NTOK * 2048 * 2);

    float* proj1 = proj01 + (size_t)NTOK * D_MODEL;
    float* cq1   = cq01   + (size_t)NTOK * D_MODEL;
    float* f1p1  = f1p01  + (size_t)NTOK * 2048;

    cvt_all_kernel<<<2048, 256, 0, stream>>>(sa_qkv_w, sa_out_w, ca_qkv_w,
                                             ca_out_w, ff1_w, ff2_w, wb_sa_qkv);
    fusedpool_kernel<<<NTOK, 256, 0, stream>>>(x, pooler_w, pooler_b, pos, h, hb, memb);

    // both layers' cross-attn K/V depend only on memb: one DUAL dispatch up front
    gemm8_kernel<0, true, false><<<768, 512, 0, stream>>>(
        memb, wb_ca_qkv + (size_t)1536 * D_MODEL, ca_qkv_b + 1536,
        ckv0, 3072, D_MODEL, 384,
        memb, wb_ca_qkv + E_QKV + (size_t)1536 * D_MODEL, ca_qkv_b + 4608 + 1536,
        ckv1, 3072);

    for (int i = 0; i < 2; ++i) {
        float* ckv = i ? ckv1 : ckv0;

        gemm8_kernel<0, false, false><<<16 * 36, 512, 0, stream>>>(
            hb, wb_sa_qkv + (size_t)i * E_QKV, sa_qkv_b + (size_t)i * 4608,
            qkv, 4608, D_MODEL, 0, nullptr, nullptr, nullptr, nullptr, 0);
        attn_kernel<true, false><<<BB * NH * 4, 256, 0, stream>>>(
            qkv, nullptr, 4608, 0, qkv, 4608, 1536, qkv, 4608, 3072, attno);
        gemm8_kernel<0, false, true><<<16 * 12 * 2, 512, 0, stream>>>(
            attno, wb_sa_out + (size_t)i * E_SQ, sa_out_b + (size_t)i * D_MODEL,
            proj01, D_MODEL, D_MODEL, 0, nullptr, nullptr, nullptr, nullptr, 0);
        ln_kernel<true, false><<<NTOK, 256, 0, stream>>>(
            h, proj01, proj1, ln1_w + i * D_MODEL, ln1_b + i * D_MODEL, h, hb, nullptr);

        gemm8_kernel<0, false, true><<<16 * 12 * 2, 512, 0, stream>>>(
            hb, wb_ca_qkv + (size_t)i * E_QKV, ca_qkv_b + (size_t)i * 4608,
            cq01, D_MODEL, D_MODEL, 0, nullptr, nullptr, nullptr, nullptr, 0);
        attn_kernel<false, true><<<BB * NH * 4, 256, 0, stream>>>(
            cq01, cq1, 1536, 0, ckv, 3072, 0, ckv, 3072, 1536, attno);
        gemm8_kernel<0, false, true><<<16 * 12 * 2, 512, 0, stream>>>(
            attno, wb_ca_out + (size_t)i * E_SQ, ca_out_b + (size_t)i * D_MODEL,
            proj01, D_MODEL, D_MODEL, 0, nullptr, nullptr, nullptr, nullptr, 0);
        ln_kernel<true, false><<<NTOK, 256, 0, stream>>>(
            h, proj01, proj1, ln2_w + i * D_MODEL, ln2_b + i * D_MODEL, h, hb, nullptr);

        gemm8_kernel<0, false, true><<<16 * 16 * 2, 512, 0, stream>>>(
            hb, wb_ff1 + (size_t)i * E_F1, ff1_b + (size_t)i * 2048,
            f1p01, 2048, D_MODEL, 0, nullptr, nullptr, nullptr, nullptr, 0);
        reduce_relu_kernel<<<2048, 256, 0, stream>>>(
            f1p01, f1p1, ffmid, NTOK * 2048 / 4);
        gemm8_kernel<0, false, true><<<16 * 12 * 2, 512, 0, stream>>>(
            ffmid, wb_ff2 + (size_t)i * E_F1, ff2_b + (size_t)i * D_MODEL,
            proj01, D_MODEL, 2048, 0, nullptr, nullptr, nullptr, nullptr, 0);
        if (i == 0)
            ln_kernel<true, false><<<NTOK, 256, 0, stream>>>(
                h, proj01, proj1, ln3_w, ln3_b, h, hb, nullptr);
        else
            ln_kernel<true, true><<<NTOK, 256, 0, stream>>>(
                h, proj01, proj1, ln3_w + D_MODEL, ln3_b + D_MODEL, h, hb, outp);
    }
}

// Round 9
// 682.257 us; speedup vs baseline: 2.5381x; 1.0191x over previous
//
#include <hip/hip_runtime.h>
#include <math.h>

#define D_MODEL 1536
#define NH      8
#define HD      192
#define BB      16
#define LL      64
#define UU      64
#define NTOK    1024
#define EPSF    1e-5f

typedef __bf16 bf16;
typedef __bf16 bf16x4_t __attribute__((ext_vector_type(4)));
typedef __bf16 bf16x8_t __attribute__((ext_vector_type(8)));
typedef float  f32x4_t  __attribute__((ext_vector_type(4)));

__device__ __forceinline__ void gload_lds16(const bf16* g, bf16* l) {
    __builtin_amdgcn_global_load_lds((const __attribute__((address_space(1))) void*)g,
                                     (__attribute__((address_space(3))) void*)l, 16, 0, 0);
}

// ---------------- all-weights fp32 -> bf16 (dst segments contiguous) ------
__global__ __launch_bounds__(256)
void cvt_all_kernel(const float* __restrict__ s0, const float* __restrict__ s1,
                    const float* __restrict__ s2, const float* __restrict__ s3,
                    const float* __restrict__ s4, const float* __restrict__ s5,
                    bf16* __restrict__ dst)
{
    const int c0 = 3538944, c1 = 4718592, c2 = 8257536,
              c3 = 9437184, c4 = 11010048, c5 = 12582912;   // float4 boundaries
    for (int i = blockIdx.x * 256 + threadIdx.x; i < c5; i += gridDim.x * 256) {
        const float* s; int j;
        if      (i < c0) { s = s0; j = i; }
        else if (i < c1) { s = s1; j = i - c0; }
        else if (i < c2) { s = s2; j = i - c1; }
        else if (i < c3) { s = s3; j = i - c2; }
        else if (i < c4) { s = s4; j = i - c3; }
        else             { s = s5; j = i - c4; }
        const float4 v = ((const float4*)s)[j];
        bf16x4_t o = { (bf16)v.x, (bf16)v.y, (bf16)v.z, (bf16)v.w };
        ((bf16x4_t*)dst)[i] = o;
    }
}

// ---------------- fused pooling: softmax(x@pw) @ x + pos, one x pass ------
__global__ __launch_bounds__(256)
void fusedpool_kernel(const float* __restrict__ x, const float* __restrict__ pw,
                      const float* __restrict__ pb, const float* __restrict__ pos,
                      float* __restrict__ h, bf16* __restrict__ hb,
                      bf16* __restrict__ memb)
{
    __shared__ float red[2][4];
    const int t = threadIdx.x, wave = t >> 6, lane = t & 63;
    const int bl = blockIdx.x, l = bl & (LL - 1);
    const float* xb = x + (size_t)bl * UU * D_MODEL;

    float pwr[6];
#pragma unroll
    for (int j = 0; j < 6; ++j) pwr[j] = pw[t + j * 256];
    const float pb0 = pb[0];

    float xv[2][6];
#pragma unroll
    for (int j = 0; j < 6; ++j) xv[0][j] = xb[t + j * 256];

    float m = -__builtin_inff(), den = 0.f;
    float acc[6] = {0.f, 0.f, 0.f, 0.f, 0.f, 0.f};

    for (int u = 0; u < UU; ++u) {
        const int cur = u & 1;
        if (u < UU - 1) {
            const float* xn = xb + (size_t)(u + 1) * D_MODEL;
#pragma unroll
            for (int j = 0; j < 6; ++j) xv[cur ^ 1][j] = xn[t + j * 256];
        }
        float p = 0.f;
#pragma unroll
        for (int j = 0; j < 6; ++j) p += xv[cur][j] * pwr[j];
#pragma unroll
        for (int off = 32; off; off >>= 1) p += __shfl_xor(p, off, 64);
        if (lane == 0) red[cur][wave] = p;
        __syncthreads();
        const float logit = red[cur][0] + red[cur][1] + red[cur][2] + red[cur][3] + pb0;
        const float nm = fmaxf(m, logit);
        const float sc = __expf(m - nm);
        const float w  = __expf(logit - nm);
#pragma unroll
        for (int j = 0; j < 6; ++j) acc[j] = acc[j] * sc + w * xv[cur][j];
        den = den * sc + w;
        m = nm;
    }

    const float inv = 1.f / den;
    const size_t db = (size_t)bl * D_MODEL;
    const int pp = l * D_MODEL;
#pragma unroll
    for (int j = 0; j < 6; ++j) {
        const int d = t + j * 256;
        const float v = acc[j] * inv + pos[pp + d];
        h[db + d] = v;
        hb[db + d] = (bf16)v;
        memb[db + d] = (bf16)v;
    }
}

// ---------------- bf16 GEMM, 8-wave, counted-vmcnt dbuf pipeline ----------
// C = A(M=1024,K) @ W(N,K)^T + bias.  BM=64, BN=128, BK=64.
// 8 waves 2m x 4n, each 32x32 (acc[2][2]).
// K-loop: T4 counted vmcnt(3) keeps next tile's 3 global_load_lds in flight
// across barriers (no vmcnt(0) drain except last tile).
// MODE 0: fp32 out; 1: relu+bf16 out.
// DUAL: vid>=split runs problem 2.  SPLITK: grid doubled, kslice=vid&1,
//   each slice does K/2; partials to Cp + kslice*NTOK*N; bias only slice 0.
template<int MODE, bool DUAL, bool SPLITK>
__global__ __launch_bounds__(512, 4)
void gemm8_kernel(const bf16* __restrict__ A, const bf16* __restrict__ W,
                  const float* __restrict__ bias, void* __restrict__ Cv,
                  int N, int K, int split,
                  const bf16* __restrict__ A2, const bf16* __restrict__ W2,
                  const float* __restrict__ bias2, void* __restrict__ Cv2, int N2)
{
    __shared__ bf16 As[2][64 * 64];
    __shared__ bf16 Bs[2][128 * 64];
    const int t = threadIdx.x, wave = t >> 6, lane = t & 63;

    // XCD-chunked bijective swizzle (all grids multiple of 8)
    const int T = gridDim.x, fid = blockIdx.x;
    int vid = (fid & 7) * (T >> 3) + (fid >> 3);
    const bf16* Ap = A; const bf16* Wp = W; const float* bp = bias;
    void* Cp = Cv; int Nn = N;
    if (DUAL && vid >= split) { vid -= split; Ap = A2; Wp = W2; bp = bias2; Cp = Cv2; Nn = N2; }
    int kslice = 0;
    if (SPLITK) { kslice = vid & 1; vid >>= 1; }
    const int m0 = (vid & 15) * 64;        // M/BM == 16 (M=1024)
    const int n0 = (vid >> 4) * 128;
    const int kbase = SPLITK ? kslice * (K >> 1) : 0;

    const int wm = wave >> 2, wn = wave & 3;     // 2m x 4n waves
    const int frow = lane & 15, kq = lane >> 4, s = frow & 7;
    const int lr = lane >> 3;
    const int g8 = ((lane & 7) ^ lr) * 8;        // pre-swizzled source granule

    f32x4_t acc[2][2] = {};

    const bf16* Abase = Ap + (size_t)(m0 + wave * 8 + lr) * K + kbase + g8;
    const bf16* Wbase = Wp + (size_t)(n0 + wave * 8 + lr) * K + kbase + g8;

    auto STAGE = [&](int buf, int tile) {
        const int k0 = tile << 6;
        gload_lds16(Abase + k0, &As[buf][wave * 512]);
        gload_lds16(Wbase + k0, &Bs[buf][wave * 512]);
        gload_lds16(Wbase + k0 + (size_t)64 * K, &Bs[buf][4096 + wave * 512]);
    };
    auto COMPUTE = [&](int buf) {
#pragma unroll
        for (int kk = 0; kk < 2; ++kk) {
            const int gg = (((kk << 2) | kq) ^ s) * 8;
            bf16x8_t af[2], bv[2];
#pragma unroll
            for (int mi = 0; mi < 2; ++mi)
                af[mi] = *(const bf16x8_t*)&As[buf][(wm * 32 + mi * 16 + frow) * 64 + gg];
#pragma unroll
            for (int ni = 0; ni < 2; ++ni)
                bv[ni] = *(const bf16x8_t*)&Bs[buf][(wn * 32 + ni * 16 + frow) * 64 + gg];
#pragma unroll
            for (int mi = 0; mi < 2; ++mi)
#pragma unroll
                for (int ni = 0; ni < 2; ++ni)
                    acc[mi][ni] = __builtin_amdgcn_mfma_f32_16x16x32_bf16(af[mi], bv[ni], acc[mi][ni], 0, 0, 0);
        }
    };

    const int nt = SPLITK ? (K >> 7) : (K >> 6);   // always >= 12
    // prologue: 2 tiles in flight (6 vmcnt ops/thread)
    STAGE(0, 0);
    STAGE(1, 1);
    for (int tt = 0; tt + 1 < nt; ++tt) {
        // wait own oldest 3 (tile tt); barrier => ALL waves' tile tt landed
        asm volatile("s_waitcnt vmcnt(3)" ::: "memory");
        __builtin_amdgcn_s_barrier();
        COMPUTE(tt & 1);
        // ds_reads complete before each wave's MFMAs issue (compiler lgkmcnt),
        // hence before this barrier; then buffer tt&1 is safe to re-stage.
        __builtin_amdgcn_s_barrier();
        if (tt + 2 < nt) STAGE(tt & 1, tt + 2);
    }
    asm volatile("s_waitcnt vmcnt(0)" ::: "memory");
    __builtin_amdgcn_s_barrier();
    COMPUTE((nt - 1) & 1);

    float* Cpart = (float*)Cp + (SPLITK ? (size_t)kslice * NTOK * Nn : 0);
    const int crow = m0 + wm * 32 + kq * 4;
    const int ccol = n0 + wn * 32 + frow;
#pragma unroll
    for (int mi = 0; mi < 2; ++mi)
#pragma unroll
        for (int ni = 0; ni < 2; ++ni) {
            const int col = ccol + ni * 16;
            const float bvv = (SPLITK && kslice) ? 0.f : bp[col];
            const int rb = crow + mi * 16;
#pragma unroll
            for (int j = 0; j < 4; ++j) {
                float v = acc[mi][ni][j] + bvv;
                if (MODE == 0) {
                    Cpart[(size_t)(rb + j) * Nn + col] = v;
                } else {
                    ((bf16*)Cp)[(size_t)(rb + j) * Nn + col] = (bf16)fmaxf(v, 0.f);
                }
            }
        }
}

// ---------------- split-K reduce + relu -> bf16 (for ff1) -----------------
__global__ __launch_bounds__(256)
void reduce_relu_kernel(const float* __restrict__ p0, const float* __restrict__ p1,
                        bf16* __restrict__ dst, int n4)
{
    const int i = blockIdx.x * 256 + threadIdx.x;
    if (i >= n4) return;
    const float4 a = ((const float4*)p0)[i];
    const float4 b = ((const float4*)p1)[i];
    bf16x4_t o = { (bf16)fmaxf(a.x + b.x, 0.f), (bf16)fmaxf(a.y + b.y, 0.f),
                   (bf16)fmaxf(a.z + b.z, 0.f), (bf16)fmaxf(a.w + b.w, 0.f) };
    ((bf16x4_t*)dst)[i] = o;
}

// ---------------- fp32 attention, 4 q-chunks per (b,h) --------------------
// QSPLIT: q = qbuf + qbuf2 (split-K partials; bias already in partial 0)
template<bool CAUSAL, bool QSPLIT>
__global__ __launch_bounds__(256)
void attn_kernel(const float* __restrict__ qbuf, const float* __restrict__ qbuf2,
                 int qstride, int qoff0,
                 const float* __restrict__ kbuf, int kstride, int koff0,
                 const float* __restrict__ vbuf, int vstride, int voff0,
                 bf16* __restrict__ out)
{
    __shared__ float kv[HD * 64];    // K phase: K^T swizzled [d][k]; V phase: [k][d]
    __shared__ float sc[16 * 64];    // this chunk's P rows
    const int t = threadIdx.x, wave = t >> 6, lane = t & 63;
    const int bh = blockIdx.x >> 2, qh = blockIdx.x & 3;
    const int b = bh >> 3, hh = bh & 7;
    const int t0 = b * 64;
    const float scale = rsqrtf((float)HD);

    for (int i = 0; i < 48; ++i) {
        const int idx = t + i * 256;
        const int r = idx / HD, c = idx % HD;
        kv[c * 64 + (r ^ (c & 31))] = kbuf[(size_t)(t0 + r) * kstride + koff0 + hh * HD + c];
    }
    __syncthreads();

    for (int qi = 0; qi < 4; ++qi) {
        const int ql = wave * 4 + qi;
        const int q = qh * 16 + ql;
        const size_t qb0 = (size_t)(t0 + q) * qstride + qoff0 + hh * HD;
        const float* qr  = qbuf + qb0;
        const float* qr2 = QSPLIT ? (qbuf2 + qb0) : nullptr;
        float a = 0.f;
#pragma unroll 8
        for (int d = 0; d < HD; ++d) {
            const float qv = QSPLIT ? (qr[d] + qr2[d]) : qr[d];
            a += qv * kv[d * 64 + (lane ^ (d & 31))];
        }
        a *= scale;
        if (CAUSAL && lane > q) a = -__builtin_inff();
        float m = a;
#pragma unroll
        for (int off = 32; off; off >>= 1) m = fmaxf(m, __shfl_xor(m, off, 64));
        float e = (CAUSAL && lane > q) ? 0.f : __expf(a - m);
        float s = e;
#pragma unroll
        for (int off = 32; off; off >>= 1) s += __shfl_xor(s, off, 64);
        sc[ql * 64 + lane] = e / s;
    }
    __syncthreads();

    for (int i = 0; i < 48; ++i) {
        const int idx = t + i * 256;
        const int r = idx / HD, c = idx % HD;
        kv[r * HD + c] = vbuf[(size_t)(t0 + r) * vstride + voff0 + hh * HD + c];
    }
    __syncthreads();

    for (int qi = 0; qi < 4; ++qi) {
        const int ql = wave * 4 + qi;
        const int q = qh * 16 + ql;
        float o0 = 0.f, o1 = 0.f, o2 = 0.f;
#pragma unroll 8
        for (int k = 0; k < 64; ++k) {
            const float p = sc[ql * 64 + k];
            o0 += p * kv[k * HD + lane];
            o1 += p * kv[k * HD + 64 + lane];
            o2 += p * kv[k * HD + 128 + lane];
        }
        bf16* op = out + (size_t)(t0 + q) * D_MODEL + hh * HD;
        op[lane] = (bf16)o0; op[64 + lane] = (bf16)o1; op[128 + lane] = (bf16)o2;
    }
}

// ---------------- residual + LayerNorm (3-input, optional slice-out) ------
// out = LN(a + r + r2); r2 is the second split-K partial.
template<bool R2, bool SLICE>
__global__ __launch_bounds__(256)
void ln_kernel(const float* __restrict__ a, const float* __restrict__ r,
               const float* __restrict__ r2,
               const float* __restrict__ w, const float* __restrict__ bb,
               float* __restrict__ out, bf16* __restrict__ outb,
               float* __restrict__ out2)
{
    __shared__ float red[8];
    const int tok = blockIdx.x, t = threadIdx.x;
    const int wave = t >> 6, lane = t & 63;
    const float* ap = a + (size_t)tok * D_MODEL;
    const float* rp = r + (size_t)tok * D_MODEL;
    const float* rp2 = R2 ? (r2 + (size_t)tok * D_MODEL) : nullptr;
    float v[6];
    float s = 0.f;
#pragma unroll
    for (int j = 0; j < 6; ++j) {
        v[j] = ap[t + j * 256] + rp[t + j * 256];
        if (R2) v[j] += rp2[t + j * 256];
        s += v[j];
    }
#pragma unroll
    for (int off = 32; off; off >>= 1) s += __shfl_xor(s, off, 64);
    if (lane == 0) red[wave] = s;
    __syncthreads();
    const float mu = (red[0] + red[1] + red[2] + red[3]) * (1.f / D_MODEL);
    float s2 = 0.f;
#pragma unroll
    for (int j = 0; j < 6; ++j) { const float d = v[j] - mu; s2 += d * d; }
#pragma unroll
    for (int off = 32; off; off >>= 1) s2 += __shfl_xor(s2, off, 64);
    if (lane == 0) red[4 + wave] = s2;
    __syncthreads();
    const float var = (red[4] + red[5] + red[6] + red[7]) * (1.f / D_MODEL);
    const float inv = rsqrtf(var + EPSF);
    const int bq = tok >> 6, lq = tok & 63;
#pragma unroll
    for (int j = 0; j < 6; ++j) {
        const int d = t + j * 256;
        const float o = (v[j] - mu) * inv * w[d] + bb[d];
        out[(size_t)tok * D_MODEL + d] = o;
        outb[(size_t)tok * D_MODEL + d] = (bf16)o;
        if (SLICE && lq < 63) out2[(size_t)(bq * 63 + lq) * D_MODEL + d] = o;
    }
}

extern "C" void kernel_launch(void* const* d_in, const int* in_sizes, int n_in,
                              void* d_out, int out_size, void* d_ws, size_t ws_size,
                              hipStream_t stream)
{
    (void)in_sizes; (void)n_in; (void)out_size; (void)ws_size;
    const float* x        = (const float*)d_in[0];
    const float* pooler_w = (const float*)d_in[1];
    const float* pooler_b = (const float*)d_in[2];
    const float* pos      = (const float*)d_in[3];
    const float* sa_qkv_w = (const float*)d_in[4];
    const float* sa_qkv_b = (const float*)d_in[5];
    const float* sa_out_w = (const float*)d_in[6];
    const float* sa_out_b = (const float*)d_in[7];
    const float* ca_qkv_w = (const float*)d_in[8];
    const float* ca_qkv_b = (const float*)d_in[9];
    const float* ca_out_w = (const float*)d_in[10];
    const float* ca_out_b = (const float*)d_in[11];
    const float* ff1_w    = (const float*)d_in[12];
    const float* ff1_b    = (const float*)d_in[13];
    const float* ff2_w    = (const float*)d_in[14];
    const float* ff2_b    = (const float*)d_in[15];
    const float* ln1_w    = (const float*)d_in[16];
    const float* ln1_b    = (const float*)d_in[17];
    const float* ln2_w    = (const float*)d_in[18];
    const float* ln2_b    = (const float*)d_in[19];
    const float* ln3_w    = (const float*)d_in[20];
    const float* ln3_b    = (const float*)d_in[21];
    float* outp = (float*)d_out;

    char* ws = (char*)d_ws;
    size_t off = 0;
    auto alloc = [&](size_t bytes) { char* p = ws + off; off += (bytes + 255) & ~(size_t)255; return p; };

    const size_t E_QKV = (size_t)4608 * D_MODEL;
    const size_t E_SQ  = (size_t)D_MODEL * D_MODEL;
    const size_t E_F1  = (size_t)2048 * D_MODEL;

    // contiguous bf16 weight block (order must match cvt_all boundaries)
    bf16* wb_sa_qkv = (bf16*)alloc(2 * E_QKV * 2);
    bf16* wb_sa_out = (bf16*)alloc(2 * E_SQ * 2);
    bf16* wb_ca_qkv = (bf16*)alloc(2 * E_QKV * 2);
    bf16* wb_ca_out = (bf16*)alloc(2 * E_SQ * 2);
    bf16* wb_ff1    = (bf16*)alloc(2 * E_F1 * 2);
    bf16* wb_ff2    = (bf16*)alloc(2 * E_F1 * 2);
    float* h     = (float*)alloc((size_t)NTOK * D_MODEL * 4);
    bf16*  hb    = (bf16*) alloc((size_t)NTOK * D_MODEL * 2);
    bf16*  memb  = (bf16*) alloc((size_t)NTOK * D_MODEL * 2);
    float* qkv   = (float*)alloc((size_t)NTOK * 4608 * 4);
    float* cq01  = (float*)alloc((size_t)NTOK * D_MODEL * 4 * 2);   // split-K pair
    float* ckv0  = (float*)alloc((size_t)NTOK * 3072 * 4);
    float* ckv1  = (float*)alloc((size_t)NTOK * 3072 * 4);
    bf16*  attno = (bf16*) alloc((size_t)NTOK * D_MODEL * 2);
    float* proj01= (float*)alloc((size_t)NTOK * D_MODEL * 4 * 2);   // split-K pair
    float* f1p01 = (float*)alloc((size_t)NTOK * 2048 * 4 * 2);      // split-K pair
    bf16*  ffmid = (bf16*) alloc((size_t)NTOK * 2048 * 2);

    float* proj1 = proj01 + (size_t)NTOK * D_MODEL;
    float* cq1   = cq01   + (size_t)NTOK * D_MODEL;
    float* f1p1  = f1p01  + (size_t)NTOK * 2048;

    cvt_all_kernel<<<2048, 256, 0, stream>>>(sa_qkv_w, sa_out_w, ca_qkv_w,
                                             ca_out_w, ff1_w, ff2_w, wb_sa_qkv);
    fusedpool_kernel<<<NTOK, 256, 0, stream>>>(x, pooler_w, pooler_b, pos, h, hb, memb);

    // both layers' cross-attn K/V depend only on memb: one DUAL dispatch up front
    gemm8_kernel<0, true, false><<<768, 512, 0, stream>>>(
        memb, wb_ca_qkv + (size_t)1536 * D_MODEL, ca_qkv_b + 1536,
        ckv0, 3072, D_MODEL, 384,
        memb, wb_ca_qkv + E_QKV + (size_t)1536 * D_MODEL, ca_qkv_b + 4608 + 1536,
        ckv1, 3072);

    for (int i = 0; i < 2; ++i) {
        float* ckv = i ? ckv1 : ckv0;

        gemm8_kernel<0, false, false><<<16 * 36, 512, 0, stream>>>(
            hb, wb_sa_qkv + (size_t)i * E_QKV, sa_qkv_b + (size_t)i * 4608,
            qkv, 4608, D_MODEL, 0, nullptr, nullptr, nullptr, nullptr, 0);
        attn_kernel<true, false><<<BB * NH * 4, 256, 0, stream>>>(
            qkv, nullptr, 4608, 0, qkv, 4608, 1536, qkv, 4608, 3072, attno);
        gemm8_kernel<0, false, true><<<16 * 12 * 2, 512, 0, stream>>>(
            attno, wb_sa_out + (size_t)i * E_SQ, sa_out_b + (size_t)i * D_MODEL,
            proj01, D_MODEL, D_MODEL, 0, nullptr, nullptr, nullptr, nullptr, 0);
        ln_kernel<true, false><<<NTOK, 256, 0, stream>>>(
            h, proj01, proj1, ln1_w + i * D_MODEL, ln1_b + i * D_MODEL, h, hb, nullptr);

        gemm8_kernel<0, false, true><<<16 * 12 * 2, 512, 0, stream>>>(
            hb, wb_ca_qkv + (size_t)i * E_QKV, ca_qkv_b + (size_t)i * 4608,
            cq01, D_MODEL, D_MODEL, 0, nullptr, nullptr, nullptr, nullptr, 0);
        attn_kernel<false, true><<<BB * NH * 4, 256, 0, stream>>>(
            cq01, cq1, 1536, 0, ckv, 3072, 0, ckv, 3072, 1536, attno);
        gemm8_kernel<0, false, true><<<16 * 12 * 2, 512, 0, stream>>>(
            attno, wb_ca_out + (size_t)i * E_SQ, ca_out_b + (size_t)i * D_MODEL,
            proj01, D_MODEL, D_MODEL, 0, nullptr, nullptr, nullptr, nullptr, 0);
        ln_kernel<true, false><<<NTOK, 256, 0, stream>>>(
            h, proj01, proj1, ln2_w + i * D_MODEL, ln2_b + i * D_MODEL, h, hb, nullptr);

        gemm8_kernel<0, false, true><<<16 * 16 * 2, 512, 0, stream>>>(
            hb, wb_ff1 + (size_t)i * E_F1, ff1_b + (size_t)i * 2048,
            f1p01, 2048, D_MODEL, 0, nullptr, nullptr, nullptr, nullptr, 0);
        reduce_relu_kernel<<<2048, 256, 0, stream>>>(
            f1p01, f1p1, ffmid, NTOK * 2048 / 4);
        gemm8_kernel<0, false, true><<<16 * 12 * 2, 512, 0, stream>>>(
            ffmid, wb_ff2 + (size_t)i * E_F1, ff2_b + (size_t)i * D_MODEL,
            proj01, D_MODEL, 2048, 0, nullptr, nullptr, nullptr, nullptr, 0);
        if (i == 0)
            ln_kernel<true, false><<<NTOK, 256, 0, stream>>>(
                h, proj01, proj1, ln3_w, ln3_b, h, hb, nullptr);
        else
            ln_kernel<true, true><<<NTOK, 256, 0, stream>>>(
                h, proj01, proj1, ln3_w + D_MODEL, ln3_b + D_MODEL, h, hb, outp);
    }
}

// Round 11
// 682.164 us; speedup vs baseline: 2.5385x; 1.0001x over previous
//
#include <hip/hip_runtime.h>
#include <math.h>

#define D_MODEL 1536
#define NH      8
#define HD      192
#define BB      16
#define LL      64
#define UU      64
#define NTOK    1024
#define EPSF    1e-5f

typedef __bf16 bf16;
typedef __bf16 bf16x4_t __attribute__((ext_vector_type(4)));
typedef __bf16 bf16x8_t __attribute__((ext_vector_type(8)));
typedef float  f32x4_t  __attribute__((ext_vector_type(4)));

__device__ __forceinline__ void gload_lds16(const bf16* g, bf16* l) {
    __builtin_amdgcn_global_load_lds((const __attribute__((address_space(1))) void*)g,
                                     (__attribute__((address_space(3))) void*)l, 16, 0, 0);
}

// ---------------- all-weights fp32 -> bf16 (dst segments contiguous) ------
__global__ __launch_bounds__(256)
void cvt_all_kernel(const float* __restrict__ s0, const float* __restrict__ s1,
                    const float* __restrict__ s2, const float* __restrict__ s3,
                    const float* __restrict__ s4, const float* __restrict__ s5,
                    bf16* __restrict__ dst)
{
    const int c0 = 3538944, c1 = 4718592, c2 = 8257536,
              c3 = 9437184, c4 = 11010048, c5 = 12582912;   // float4 boundaries
    for (int i = blockIdx.x * 256 + threadIdx.x; i < c5; i += gridDim.x * 256) {
        const float* s; int j;
        if      (i < c0) { s = s0; j = i; }
        else if (i < c1) { s = s1; j = i - c0; }
        else if (i < c2) { s = s2; j = i - c1; }
        else if (i < c3) { s = s3; j = i - c2; }
        else if (i < c4) { s = s4; j = i - c3; }
        else             { s = s5; j = i - c4; }
        const float4 v = ((const float4*)s)[j];
        bf16x4_t o = { (bf16)v.x, (bf16)v.y, (bf16)v.z, (bf16)v.w };
        ((bf16x4_t*)dst)[i] = o;
    }
}

// ---------------- fused pooling: softmax(x@pw) @ x + pos, one x pass ------
__global__ __launch_bounds__(256)
void fusedpool_kernel(const float* __restrict__ x, const float* __restrict__ pw,
                      const float* __restrict__ pb, const float* __restrict__ pos,
                      float* __restrict__ h, bf16* __restrict__ hb,
                      bf16* __restrict__ memb)
{
    __shared__ float red[2][4];
    const int t = threadIdx.x, wave = t >> 6, lane = t & 63;
    const int bl = blockIdx.x, l = bl & (LL - 1);
    const float* xb = x + (size_t)bl * UU * D_MODEL;

    float pwr[6];
#pragma unroll
    for (int j = 0; j < 6; ++j) pwr[j] = pw[t + j * 256];
    const float pb0 = pb[0];

    float xv[2][6];
#pragma unroll
    for (int j = 0; j < 6; ++j) xv[0][j] = xb[t + j * 256];

    float m = -__builtin_inff(), den = 0.f;
    float acc[6] = {0.f, 0.f, 0.f, 0.f, 0.f, 0.f};

    for (int u = 0; u < UU; ++u) {
        const int cur = u & 1;
        if (u < UU - 1) {
            const float* xn = xb + (size_t)(u + 1) * D_MODEL;
#pragma unroll
            for (int j = 0; j < 6; ++j) xv[cur ^ 1][j] = xn[t + j * 256];
        }
        float p = 0.f;
#pragma unroll
        for (int j = 0; j < 6; ++j) p += xv[cur][j] * pwr[j];
#pragma unroll
        for (int off = 32; off; off >>= 1) p += __shfl_xor(p, off, 64);
        if (lane == 0) red[cur][wave] = p;
        __syncthreads();
        const float logit = red[cur][0] + red[cur][1] + red[cur][2] + red[cur][3] + pb0;
        const float nm = fmaxf(m, logit);
        const float sc = __expf(m - nm);
        const float w  = __expf(logit - nm);
#pragma unroll
        for (int j = 0; j < 6; ++j) acc[j] = acc[j] * sc + w * xv[cur][j];
        den = den * sc + w;
        m = nm;
    }

    const float inv = 1.f / den;
    const size_t db = (size_t)bl * D_MODEL;
    const int pp = l * D_MODEL;
#pragma unroll
    for (int j = 0; j < 6; ++j) {
        const int d = t + j * 256;
        const float v = acc[j] * inv + pos[pp + d];
        h[db + d] = v;
        hb[db + d] = (bf16)v;
        memb[db + d] = (bf16)v;
    }
}

// ---------------- bf16 GEMM, 8-wave, counted-vmcnt dbuf pipeline ----------
// C = A(M=1024,K) @ W(N,K)^T + bias.  BM=64, BN=128, BK=64.
// 8 waves 2m x 4n, each 32x32 (acc[2][2]).
// __launch_bounds__(512,6): 24 waves/CU -> 3 blocks/CU (LDS 48KB*3=144KB ok);
// sa_qkv's 576 blocks and ckv's 768 blocks become fully co-resident.
// K-loop: T4 counted vmcnt(3) keeps next tile's loads in flight across barriers.
// MODE 0: fp32 out; 1: relu+bf16 out.
// DUAL: vid>=split runs problem 2.  SPLITK: grid doubled, kslice=vid&1,
//   each slice does K/2; partials to Cp + kslice*NTOK*N; bias only slice 0.
template<int MODE, bool DUAL, bool SPLITK>
__global__ __launch_bounds__(512, 6)
void gemm8_kernel(const bf16* __restrict__ A, const bf16* __restrict__ W,
                  const float* __restrict__ bias, void* __restrict__ Cv,
                  int N, int K, int split,
                  const bf16* __restrict__ A2, const bf16* __restrict__ W2,
                  const float* __restrict__ bias2, void* __restrict__ Cv2, int N2)
{
    __shared__ bf16 As[2][64 * 64];
    __shared__ bf16 Bs[2][128 * 64];
    const int t = threadIdx.x, wave = t >> 6, lane = t & 63;

    // XCD-chunked bijective swizzle (all grids multiple of 8)
    const int T = gridDim.x, fid = blockIdx.x;
    int vid = (fid & 7) * (T >> 3) + (fid >> 3);
    const bf16* Ap = A; const bf16* Wp = W; const float* bp = bias;
    void* Cp = Cv; int Nn = N;
    if (DUAL && vid >= split) { vid -= split; Ap = A2; Wp = W2; bp = bias2; Cp = Cv2; Nn = N2; }
    int kslice = 0;
    if (SPLITK) { kslice = vid & 1; vid >>= 1; }
    const int m0 = (vid & 15) * 64;        // M/BM == 16 (M=1024)
    const int n0 = (vid >> 4) * 128;
    const int kbase = SPLITK ? kslice * (K >> 1) : 0;

    const int wm = wave >> 2, wn = wave & 3;     // 2m x 4n waves
    const int frow = lane & 15, kq = lane >> 4, s = frow & 7;
    const int lr = lane >> 3;
    const int g8 = ((lane & 7) ^ lr) * 8;        // pre-swizzled source granule

    f32x4_t acc[2][2] = {};

    const bf16* Abase = Ap + (size_t)(m0 + wave * 8 + lr) * K + kbase + g8;
    const bf16* Wbase = Wp + (size_t)(n0 + wave * 8 + lr) * K + kbase + g8;

    auto STAGE = [&](int buf, int tile) {
        const int k0 = tile << 6;
        gload_lds16(Abase + k0, &As[buf][wave * 512]);
        gload_lds16(Wbase + k0, &Bs[buf][wave * 512]);
        gload_lds16(Wbase + k0 + (size_t)64 * K, &Bs[buf][4096 + wave * 512]);
    };
    auto COMPUTE = [&](int buf) {
#pragma unroll
        for (int kk = 0; kk < 2; ++kk) {
            const int gg = (((kk << 2) | kq) ^ s) * 8;
            bf16x8_t af[2], bv[2];
#pragma unroll
            for (int mi = 0; mi < 2; ++mi)
                af[mi] = *(const bf16x8_t*)&As[buf][(wm * 32 + mi * 16 + frow) * 64 + gg];
#pragma unroll
            for (int ni = 0; ni < 2; ++ni)
                bv[ni] = *(const bf16x8_t*)&Bs[buf][(wn * 32 + ni * 16 + frow) * 64 + gg];
#pragma unroll
            for (int mi = 0; mi < 2; ++mi)
#pragma unroll
                for (int ni = 0; ni < 2; ++ni)
                    acc[mi][ni] = __builtin_amdgcn_mfma_f32_16x16x32_bf16(af[mi], bv[ni], acc[mi][ni], 0, 0, 0);
        }
    };

    const int nt = SPLITK ? (K >> 7) : (K >> 6);   // always >= 12
    // prologue: 2 tiles in flight (6 vmcnt ops/thread)
    STAGE(0, 0);
    STAGE(1, 1);
    for (int tt = 0; tt + 1 < nt; ++tt) {
        // wait own oldest 3 (tile tt); barrier => ALL waves' tile tt landed
        asm volatile("s_waitcnt vmcnt(3)" ::: "memory");
        __builtin_amdgcn_s_barrier();
        COMPUTE(tt & 1);
        // ds_reads complete before each wave's MFMAs issue (compiler lgkmcnt),
        // hence before this barrier; then buffer tt&1 is safe to re-stage.
        __builtin_amdgcn_s_barrier();
        if (tt + 2 < nt) STAGE(tt & 1, tt + 2);
    }
    asm volatile("s_waitcnt vmcnt(0)" ::: "memory");
    __builtin_amdgcn_s_barrier();
    COMPUTE((nt - 1) & 1);

    float* Cpart = (float*)Cp + (SPLITK ? (size_t)kslice * NTOK * Nn : 0);
    const int crow = m0 + wm * 32 + kq * 4;
    const int ccol = n0 + wn * 32 + frow;
#pragma unroll
    for (int mi = 0; mi < 2; ++mi)
#pragma unroll
        for (int ni = 0; ni < 2; ++ni) {
            const int col = ccol + ni * 16;
            const float bvv = (SPLITK && kslice) ? 0.f : bp[col];
            const int rb = crow + mi * 16;
#pragma unroll
            for (int j = 0; j < 4; ++j) {
                float v = acc[mi][ni][j] + bvv;
                if (MODE == 0) {
                    Cpart[(size_t)(rb + j) * Nn + col] = v;
                } else {
                    ((bf16*)Cp)[(size_t)(rb + j) * Nn + col] = (bf16)fmaxf(v, 0.f);
                }
            }
        }
}

// ---------------- split-K reduce + relu -> bf16 (for ff1) -----------------
__global__ __launch_bounds__(256)
void reduce_relu_kernel(const float* __restrict__ p0, const float* __restrict__ p1,
                        bf16* __restrict__ dst, int n4)
{
    const int i = blockIdx.x * 256 + threadIdx.x;
    if (i >= n4) return;
    const float4 a = ((const float4*)p0)[i];
    const float4 b = ((const float4*)p1)[i];
    bf16x4_t o = { (bf16)fmaxf(a.x + b.x, 0.f), (bf16)fmaxf(a.y + b.y, 0.f),
                   (bf16)fmaxf(a.z + b.z, 0.f), (bf16)fmaxf(a.w + b.w, 0.f) };
    ((bf16x4_t*)dst)[i] = o;
}

// ---------------- fp32 attention, 4 q-chunks per (b,h) --------------------
// QSPLIT: q = qbuf + qbuf2 (split-K partials; bias already in partial 0)
template<bool CAUSAL, bool QSPLIT>
__global__ __launch_bounds__(256)
void attn_kernel(const float* __restrict__ qbuf, const float* __restrict__ qbuf2,
                 int qstride, int qoff0,
                 const float* __restrict__ kbuf, int kstride, int koff0,
                 const float* __restrict__ vbuf, int vstride, int voff0,
                 bf16* __restrict__ out)
{
    __shared__ float kv[HD * 64];    // K phase: K^T swizzled [d][k]; V phase: [k][d]
    __shared__ float sc[16 * 64];    // this chunk's P rows
    const int t = threadIdx.x, wave = t >> 6, lane = t & 63;
    const int bh = blockIdx.x >> 2, qh = blockIdx.x & 3;
    const int b = bh >> 3, hh = bh & 7;
    const int t0 = b * 64;
    const float scale = rsqrtf((float)HD);

    for (int i = 0; i < 48; ++i) {
        const int idx = t + i * 256;
        const int r = idx / HD, c = idx % HD;
        kv[c * 64 + (r ^ (c & 31))] = kbuf[(size_t)(t0 + r) * kstride + koff0 + hh * HD + c];
    }
    __syncthreads();

    for (int qi = 0; qi < 4; ++qi) {
        const int ql = wave * 4 + qi;
        const int q = qh * 16 + ql;
        const size_t qb0 = (size_t)(t0 + q) * qstride + qoff0 + hh * HD;
        const float* qr  = qbuf + qb0;
        const float* qr2 = QSPLIT ? (qbuf2 + qb0) : nullptr;
        float a = 0.f;
#pragma unroll 8
        for (int d = 0; d < HD; ++d) {
            const float qv = QSPLIT ? (qr[d] + qr2[d]) : qr[d];
            a += qv * kv[d * 64 + (lane ^ (d & 31))];
        }
        a *= scale;
        if (CAUSAL && lane > q) a = -__builtin_inff();
        float m = a;
#pragma unroll
        for (int off = 32; off; off >>= 1) m = fmaxf(m, __shfl_xor(m, off, 64));
        float e = (CAUSAL && lane > q) ? 0.f : __expf(a - m);
        float s = e;
#pragma unroll
        for (int off = 32; off; off >>= 1) s += __shfl_xor(s, off, 64);
        sc[ql * 64 + lane] = e / s;
    }
    __syncthreads();

    for (int i = 0; i < 48; ++i) {
        const int idx = t + i * 256;
        const int r = idx / HD, c = idx % HD;
        kv[r * HD + c] = vbuf[(size_t)(t0 + r) * vstride + voff0 + hh * HD + c];
    }
    __syncthreads();

    for (int qi = 0; qi < 4; ++qi) {
        const int ql = wave * 4 + qi;
        const int q = qh * 16 + ql;
        float o0 = 0.f, o1 = 0.f, o2 = 0.f;
#pragma unroll 8
        for (int k = 0; k < 64; ++k) {
            const float p = sc[ql * 64 + k];
            o0 += p * kv[k * HD + lane];
            o1 += p * kv[k * HD + 64 + lane];
            o2 += p * kv[k * HD + 128 + lane];
        }
        bf16* op = out + (size_t)(t0 + q) * D_MODEL + hh * HD;
        op[lane] = (bf16)o0; op[64 + lane] = (bf16)o1; op[128 + lane] = (bf16)o2;
    }
}

// ---------------- residual + LayerNorm (3-input, optional slice-out) ------
// out = LN(a + r + r2); r2 is the second split-K partial.
template<bool R2, bool SLICE>
__global__ __launch_bounds__(256)
void ln_kernel(const float* __restrict__ a, const float* __restrict__ r,
               const float* __restrict__ r2,
               const float* __restrict__ w, const float* __restrict__ bb,
               float* __restrict__ out, bf16* __restrict__ outb,
               float* __restrict__ out2)
{
    __shared__ float red[8];
    const int tok = blockIdx.x, t = threadIdx.x;
    const int wave = t >> 6, lane = t & 63;
    const float* ap = a + (size_t)tok * D_MODEL;
    const float* rp = r + (size_t)tok * D_MODEL;
    const float* rp2 = R2 ? (r2 + (size_t)tok * D_MODEL) : nullptr;
    float v[6];
    float s = 0.f;
#pragma unroll
    for (int j = 0; j < 6; ++j) {
        v[j] = ap[t + j * 256] + rp[t + j * 256];
        if (R2) v[j] += rp2[t + j * 256];
        s += v[j];
    }
#pragma unroll
    for (int off = 32; off; off >>= 1) s += __shfl_xor(s, off, 64);
    if (lane == 0) red[wave] = s;
    __syncthreads();
    const float mu = (red[0] + red[1] + red[2] + red[3]) * (1.f / D_MODEL);
    float s2 = 0.f;
#pragma unroll
    for (int j = 0; j < 6; ++j) { const float d = v[j] - mu; s2 += d * d; }
#pragma unroll
    for (int off = 32; off; off >>= 1) s2 += __shfl_xor(s2, off, 64);
    if (lane == 0) red[4 + wave] = s2;
    __syncthreads();
    const float var = (red[4] + red[5] + red[6] + red[7]) * (1.f / D_MODEL);
    const float inv = rsqrtf(var + EPSF);
    const int bq = tok >> 6, lq = tok & 63;
#pragma unroll
    for (int j = 0; j < 6; ++j) {
        const int d = t + j * 256;
        const float o = (v[j] - mu) * inv * w[d] + bb[d];
        out[(size_t)tok * D_MODEL + d] = o;
        outb[(size_t)tok * D_MODEL + d] = (bf16)o;
        if (SLICE && lq < 63) out2[(size_t)(bq * 63 + lq) * D_MODEL + d] = o;
    }
}

extern "C" void kernel_launch(void* const* d_in, const int* in_sizes, int n_in,
                              void* d_out, int out_size, void* d_ws, size_t ws_size,
                              hipStream_t stream)
{
    (void)in_sizes; (void)n_in; (void)out_size; (void)ws_size;
    const float* x        = (const float*)d_in[0];
    const float* pooler_w = (const float*)d_in[1];
    const float* pooler_b = (const float*)d_in[2];
    const float* pos      = (const float*)d_in[3];
    const float* sa_qkv_w = (const float*)d_in[4];
    const float* sa_qkv_b = (const float*)d_in[5];
    const float* sa_out_w = (const float*)d_in[6];
    const float* sa_out_b = (const float*)d_in[7];
    const float* ca_qkv_w = (const float*)d_in[8];
    const float* ca_qkv_b = (const float*)d_in[9];
    const float* ca_out_w = (const float*)d_in[10];
    const float* ca_out_b = (const float*)d_in[11];
    const float* ff1_w    = (const float*)d_in[12];
    const float* ff1_b    = (const float*)d_in[13];
    const float* ff2_w    = (const float*)d_in[14];
    const float* ff2_b    = (const float*)d_in[15];
    const float* ln1_w    = (const float*)d_in[16];
    const float* ln1_b    = (const float*)d_in[17];
    const float* ln2_w    = (const float*)d_in[18];
    const float* ln2_b    = (const float*)d_in[19];
    const float* ln3_w    = (const float*)d_in[20];
    const float* ln3_b    = (const float*)d_in[21];
    float* outp = (float*)d_out;

    char* ws = (char*)d_ws;
    size_t off = 0;
    auto alloc = [&](size_t bytes) { char* p = ws + off; off += (bytes + 255) & ~(size_t)255; return p; };

    const size_t E_QKV = (size_t)4608 * D_MODEL;
    const size_t E_SQ  = (size_t)D_MODEL * D_MODEL;
    const size_t E_F1  = (size_t)2048 * D_MODEL;

    // contiguous bf16 weight block (order must match cvt_all boundaries)
    bf16* wb_sa_qkv = (bf16*)alloc(2 * E_QKV * 2);
    bf16* wb_sa_out = (bf16*)alloc(2 * E_SQ * 2);
    bf16* wb_ca_qkv = (bf16*)alloc(2 * E_QKV * 2);
    bf16* wb_ca_out = (bf16*)alloc(2 * E_SQ * 2);
    bf16* wb_ff1    = (bf16*)alloc(2 * E_F1 * 2);
    bf16* wb_ff2    = (bf16*)alloc(2 * E_F1 * 2);
    float* h     = (float*)alloc((size_t)NTOK * D_MODEL * 4);
    bf16*  hb    = (bf16*) alloc((size_t)NTOK * D_MODEL * 2);
    bf16*  memb  = (bf16*) alloc((size_t)NTOK * D_MODEL * 2);
    float* qkv   = (float*)alloc((size_t)NTOK * 4608 * 4);
    float* cq01  = (float*)alloc((size_t)NTOK * D_MODEL * 4 * 2);   // split-K pair
    float* ckv0  = (float*)alloc((size_t)NTOK * 3072 * 4);
    float* ckv1  = (float*)alloc((size_t)NTOK * 3072 * 4);
    bf16*  attno = (bf16*) alloc((size_t)NTOK * D_MODEL * 2);
    float* proj01= (float*)alloc((size_t)NTOK * D_MODEL * 4 * 2);   // split-K pair
    float* f1p01 = (float*)alloc((size_t)NTOK * 2048 * 4 * 2);      // split-K pair
    bf16*  ffmid = (bf16*) alloc((size_t)NTOK * 2048 * 2);

    float* proj1 = proj01 + (size_t)NTOK * D_MODEL;
    float* cq1   = cq01   + (size_t)NTOK * D_MODEL;
    float* f1p1  = f1p01  + (size_t)NTOK * 2048;

    cvt_all_kernel<<<2048, 256, 0, stream>>>(sa_qkv_w, sa_out_w, ca_qkv_w,
                                             ca_out_w, ff1_w, ff2_w, wb_sa_qkv);
    fusedpool_kernel<<<NTOK, 256, 0, stream>>>(x, pooler_w, pooler_b, pos, h, hb, memb);

    // both layers' cross-attn K/V depend only on memb: one DUAL dispatch up front
    gemm8_kernel<0, true, false><<<768, 512, 0, stream>>>(
        memb, wb_ca_qkv + (size_t)1536 * D_MODEL, ca_qkv_b + 1536,
        ckv0, 3072, D_MODEL, 384,
        memb, wb_ca_qkv + E_QKV + (size_t)1536 * D_MODEL, ca_qkv_b + 4608 + 1536,
        ckv1, 3072);

    for (int i = 0; i < 2; ++i) {
        float* ckv = i ? ckv1 : ckv0;

        gemm8_kernel<0, false, false><<<16 * 36, 512, 0, stream>>>(
            hb, wb_sa_qkv + (size_t)i * E_QKV, sa_qkv_b + (size_t)i * 4608,
            qkv, 4608, D_MODEL, 0, nullptr, nullptr, nullptr, nullptr, 0);
        attn_kernel<true, false><<<BB * NH * 4, 256, 0, stream>>>(
            qkv, nullptr, 4608, 0, qkv, 4608, 1536, qkv, 4608, 3072, attno);
        gemm8_kernel<0, false, true><<<16 * 12 * 2, 512, 0, stream>>>(
            attno, wb_sa_out + (size_t)i * E_SQ, sa_out_b + (size_t)i * D_MODEL,
            proj01, D_MODEL, D_MODEL, 0, nullptr, nullptr, nullptr, nullptr, 0);
        ln_kernel<true, false><<<NTOK, 256, 0, stream>>>(
            h, proj01, proj1, ln1_w + i * D_MODEL, ln1_b + i * D_MODEL, h, hb, nullptr);

        gemm8_kernel<0, false, true><<<16 * 12 * 2, 512, 0, stream>>>(
            hb, wb_ca_qkv + (size_t)i * E_QKV, ca_qkv_b + (size_t)i * 4608,
            cq01, D_MODEL, D_MODEL, 0, nullptr, nullptr, nullptr, nullptr, 0);
        attn_kernel<false, true><<<BB * NH * 4, 256, 0, stream>>>(
            cq01, cq1, 1536, 0, ckv, 3072, 0, ckv, 3072, 1536, attno);
        gemm8_kernel<0, false, true><<<16 * 12 * 2, 512, 0, stream>>>(
            attno, wb_ca_out + (size_t)i * E_SQ, ca_out_b + (size_t)i * D_MODEL,
            proj01, D_MODEL, D_MODEL, 0, nullptr, nullptr, nullptr, nullptr, 0);
        ln_kernel<true, false><<<NTOK, 256, 0, stream>>>(
            h, proj01, proj1, ln2_w + i * D_MODEL, ln2_b + i * D_MODEL, h, hb, nullptr);

        gemm8_kernel<0, false, true><<<16 * 16 * 2, 512, 0, stream>>>(
            hb, wb_ff1 + (size_t)i * E_F1, ff1_b + (size_t)i * 2048,
            f1p01, 2048, D_MODEL, 0, nullptr, nullptr, nullptr, nullptr, 0);
        reduce_relu_kernel<<<2048, 256, 0, stream>>>(
            f1p01, f1p1, ffmid, NTOK * 2048 / 4);
        gemm8_kernel<0, false, true><<<16 * 12 * 2, 512, 0, stream>>>(
            ffmid, wb_ff2 + (size_t)i * E_F1, ff2_b + (size_t)i * D_MODEL,
            proj01, D_MODEL, 2048, 0, nullptr, nullptr, nullptr, nullptr, 0);
        if (i == 0)
            ln_kernel<true, false><<<NTOK, 256, 0, stream>>>(
                h, proj01, proj1, ln3_w, ln3_b, h, hb, nullptr);
        else
            ln_kernel<true, true><<<NTOK, 256, 0, stream>>>(
                h, proj01, proj1, ln3_w + D_MODEL, ln3_b + D_MODEL, h, hb, outp);
    }
}